// Round 4
// baseline (128.399 us; speedup 1.0000x reference)
//
#include <hip/hip_runtime.h>
#include <math.h>

#define NB   32
#define NA   64
#define EDIM 256
#define HIS  50
#define DKA  9
#define NV   8

typedef _Float16 HALF;
typedef _Float16 half8 __attribute__((ext_vector_type(8)));
typedef float    f32x4 __attribute__((ext_vector_type(4)));

// ws layout (bytes):
#define WS_WKP   0          // f16 fragment-packed Wk                131072
#define WS_WVP   131072     // f16 fragment-packed Wv                131072
#define WS_WQI   262144     // f16 interleaved WqT [(d>>3)][e][d&7]  131072
#define WS_WOI   393216     // f16 interleaved WoutT                 131072
#define WS_PE    524288     // f32 PE [50][256]                      51200
#define WS_IDX   575488     // int idxTab [64][50]                   12800
#define WS_QH    588288     // f16 qh [2048][256]                    1048576
#define WS_ENCF  1636864    // f16 A-frags [bidx][kk=8][mt=3][64][8] 50331648
#define WS_ENC2  51968512   // f16 rows t=48,49 [bidx][2][256]       2097152
#define WS_NEED  54065664ULL

// ---------------- setup: pack weights, PE table, adjacency index ----------------
__global__ __launch_bounds__(256) void pack_setup(
    const float* __restrict__ Wk, const float* __restrict__ Wv,
    const float* __restrict__ Wq, const float* __restrict__ Wout,
    const float* __restrict__ adjs,
    char* __restrict__ ws)
{
    const int tid = blockIdx.x * 256 + threadIdx.x;   // 0..65535
    HALF* WkP  = (HALF*)(ws + WS_WKP);
    HALF* WvP  = (HALF*)(ws + WS_WVP);
    HALF* WqI  = (HALF*)(ws + WS_WQI);
    HALF* WoI  = (HALF*)(ws + WS_WOI);
    float* PE  = (float*)(ws + WS_PE);
    int*  idxT = (int*)(ws + WS_IDX);

    // B-fragment pack: out = ((ntile*8 + ktile)*64 + lane)*8 + elem
    {
        const int elem = tid & 7;
        const int lane = (tid >> 3) & 63;
        const int kt   = (tid >> 9) & 7;
        const int nt   = tid >> 12;
        const int k = kt * 32 + (lane >> 4) * 8 + elem;
        const int n = nt * 16 + (lane & 15);
        WkP[tid] = (HALF)Wk[k * EDIM + n];
        WvP[tid] = (HALF)Wv[k * EDIM + n];
    }
    // interleaved transposes for coalesced matvec: [(d>>3)][e][d&7]
    {
        const int d = tid & 255;
        const int e = tid >> 8;
        const int dst = ((d >> 3) * EDIM + e) * 8 + (d & 7);
        WqI[dst] = (HALF)Wq[d * EDIM + e];
        WoI[dst] = (HALF)Wout[d * EDIM + e];
    }
    // positional encoding table
    if (tid < HIS * EDIM) {
        const int t = tid >> 8;
        const int e = tid & 255;
        const float dt = expf(-(float)(e & ~1) * (9.210340371976184f / 256.0f));
        const float arg = (float)t * dt;
        PE[tid] = (e & 1) ? cosf(arg) : sinf(arg);
    }
    // adjacency one-hot -> index
    if (tid < NA * HIS) {
        const float* row = adjs + tid * NA;   // tid = n*HIS + t
        int best = 0;
        #pragma unroll
        for (int a = 0; a < NA; ++a) best = (row[a] > 0.5f) ? a : best;
        idxT[tid] = best;
    }
}

// ---------------- K1: enc in A-fragment order + qh, all (b,n) ----------------
__global__ __launch_bounds__(256) void enc_kernel(
    const float* __restrict__ q,
    const float* __restrict__ kin,
    const float* __restrict__ bq,
    const float* __restrict__ Wenc,
    const char*  __restrict__ ws,
    char* __restrict__ wsout)
{
    const int tid  = threadIdx.x;
    const int bidx = blockIdx.x;
    const int b = bidx >> 6;
    const int n = bidx & 63;
    const int lane = tid & 63;
    const int w    = tid >> 6;

    const HALF* WqI = (const HALF*)(ws + WS_WQI);
    const float* PE = (const float*)(ws + WS_PE);
    const int* idxT = (const int*)(ws + WS_IDX);
    HALF* qh   = (HALF*)(wsout + WS_QH);
    HALF* encF = (HALF*)(wsout + WS_ENCF);
    HALF* enc2 = (HALF*)(wsout + WS_ENC2);

    __shared__ __align__(16) float s_q[EDIM];
    __shared__ __align__(16) float s_neigh[HIS][12];

    s_q[tid] = q[bidx * EDIM + tid];
    for (int i = tid; i < HIS * 12; i += 256) {
        const int t = i / 12;
        const int d = i - t * 12;
        float val = 0.0f;
        if (d < DKA) val = kin[((b * HIS + t) * NA + idxT[n * HIS + t]) * DKA + d];
        s_neigh[t][d] = val;
    }
    __syncthreads();

    // qh matvec (coalesced interleaved weights)
    {
        const int e = tid;
        float acc = bq[e];
        #pragma unroll 4
        for (int j = 0; j < 32; ++j) {
            const half8 hv = *reinterpret_cast<const half8*>(&WqI[(j * EDIM + e) * 8]);
            const float4 q0 = *reinterpret_cast<const float4*>(&s_q[j * 8]);
            const float4 q1 = *reinterpret_cast<const float4*>(&s_q[j * 8 + 4]);
            acc += q0.x*(float)hv[0] + q0.y*(float)hv[1] + q0.z*(float)hv[2] + q0.w*(float)hv[3]
                 + q1.x*(float)hv[4] + q1.y*(float)hv[5] + q1.z*(float)hv[6] + q1.w*(float)hv[7];
        }
        qh[bidx * EDIM + e] = (HALF)fmaxf(acc, 0.0f);
    }

    // enc rows in fragment order. Lane L=lane&31 owns e = 8L..8L+7.
    // Wave-half (lane>>5) picks t parity; wave w covers t-pairs tp = w, w+4, ...
    {
        const int L  = lane & 31;
        const int th = lane >> 5;
        const int e0 = L * 8;
        float4 weA[DKA], weB[DKA];
        #pragma unroll
        for (int d = 0; d < DKA; ++d) {
            weA[d] = *reinterpret_cast<const float4*>(&Wenc[d * EDIM + e0]);
            weB[d] = *reinterpret_cast<const float4*>(&Wenc[d * EDIM + e0 + 4]);
        }

        for (int tp = w; tp < 25; tp += 4) {
            const int t = 2 * tp + th;      // 0..49
            float nv[DKA];
            #pragma unroll
            for (int d = 0; d < DKA; ++d) nv[d] = s_neigh[t][d];
            float4 xA = nv[0] * weA[0];
            float4 xB = nv[0] * weB[0];
            #pragma unroll
            for (int d = 1; d < DKA; ++d) { xA += nv[d] * weA[d]; xB += nv[d] * weB[d]; }
            const float4 peA = *reinterpret_cast<const float4*>(&PE[t * EDIM + e0]);
            const float4 peB = *reinterpret_cast<const float4*>(&PE[t * EDIM + e0 + 4]);
            float r0 = 0.5f * xA.x * (1.0f + erff(xA.x * 0.70710678118654752f)) + peA.x;
            float r1 = 0.5f * xA.y * (1.0f + erff(xA.y * 0.70710678118654752f)) + peA.y;
            float r2 = 0.5f * xA.z * (1.0f + erff(xA.z * 0.70710678118654752f)) + peA.z;
            float r3 = 0.5f * xA.w * (1.0f + erff(xA.w * 0.70710678118654752f)) + peA.w;
            float r4 = 0.5f * xB.x * (1.0f + erff(xB.x * 0.70710678118654752f)) + peB.x;
            float r5 = 0.5f * xB.y * (1.0f + erff(xB.y * 0.70710678118654752f)) + peB.y;
            float r6 = 0.5f * xB.z * (1.0f + erff(xB.z * 0.70710678118654752f)) + peB.z;
            float r7 = 0.5f * xB.w * (1.0f + erff(xB.w * 0.70710678118654752f)) + peB.w;
            half8 hv;
            hv[0] = (HALF)r0; hv[1] = (HALF)r1; hv[2] = (HALF)r2; hv[3] = (HALF)r3;
            hv[4] = (HALF)r4; hv[5] = (HALF)r5; hv[6] = (HALF)r6; hv[7] = (HALF)r7;
            if (t < 48) {
                const int kk = L >> 2;                  // e0>>5
                const int mt = t >> 4;
                const int fl = (L & 3) * 16 + (t & 15); // fragment lane
                const size_t off = ((((size_t)bidx * 8 + kk) * 3 + mt) * 64 + fl) * 8;
                *reinterpret_cast<half8*>(&encF[off]) = hv;
            } else {
                const size_t off = (((size_t)bidx * 2 + (t - 48)) * EDIM) + e0;
                *reinterpret_cast<half8*>(&enc2[off]) = hv;
            }
        }
    }
}

// ---------------- K2: attention per (b,n), per-wave autonomous ----------------
__global__ __launch_bounds__(256) void attn_kernel(
    const float* __restrict__ bk,
    const float* __restrict__ bv,
    const float* __restrict__ bout,
    const char*  __restrict__ ws,
    float* __restrict__ out)
{
    const int tid  = threadIdx.x;
    const int bidx = blockIdx.x;
    const int lane = tid & 63;
    const int w    = tid >> 6;
    const int l15  = lane & 15;
    const int l4   = lane >> 4;

    const HALF* WkP  = (const HALF*)(ws + WS_WKP);
    const HALF* WvP  = (const HALF*)(ws + WS_WVP);
    const HALF* WoI  = (const HALF*)(ws + WS_WOI);
    const HALF* qh   = (const HALF*)(ws + WS_QH);
    const HALF* encF = (const HALF*)(ws + WS_ENCF);
    const HALF* enc2 = (const HALF*)(ws + WS_ENC2);

    __shared__ float s_att[4][2][64];     // per-wave private
    __shared__ __align__(16) float s_o[EDIM];

    // ---- pass 1: kh GEMM -> logits ----
    f32x4 acc[4][4];
    #pragma unroll
    for (int mt = 0; mt < 4; ++mt)
        #pragma unroll
        for (int nt = 0; nt < 4; ++nt) acc[mt][nt] = (f32x4)0.0f;

    const size_t fbase = (size_t)bidx * 8;
    #pragma unroll 2
    for (int kk = 0; kk < 8; ++kk) {
        half8 afr[4];
        #pragma unroll
        for (int mt = 0; mt < 3; ++mt)
            afr[mt] = *reinterpret_cast<const half8*>(
                &encF[(((fbase + kk) * 3 + mt) * 64 + lane) * 8]);
        afr[3] = (half8)(HALF)0.0f;
        if (l15 < 2)
            afr[3] = *reinterpret_cast<const half8*>(
                &enc2[((size_t)bidx * 2 + l15) * EDIM + kk * 32 + l4 * 8]);
        #pragma unroll
        for (int nt = 0; nt < 4; ++nt) {
            const half8 bfr = *reinterpret_cast<const half8*>(
                WkP + ((size_t)((w * 4 + nt) * 8 + kk) * 64 + lane) * 8);
            #pragma unroll
            for (int mt = 0; mt < 4; ++mt)
                acc[mt][nt] = __builtin_amdgcn_mfma_f32_16x16x32_f16(afr[mt], bfr, acc[mt][nt], 0, 0, 0);
        }
    }

    {
        float qv[4], bkb[4];
        #pragma unroll
        for (int nt = 0; nt < 4; ++nt) {
            const int col = w * 64 + nt * 16 + l15;
            qv[nt]  = (float)qh[bidx * EDIM + col];
            bkb[nt] = bk[col];
        }
        #pragma unroll
        for (int mt = 0; mt < 4; ++mt)
            #pragma unroll
            for (int r = 0; r < 4; ++r) {
                float p0 = qv[0] * fmaxf(acc[mt][0][r] + bkb[0], 0.0f)
                         + qv[1] * fmaxf(acc[mt][1][r] + bkb[1], 0.0f);
                float p1 = qv[2] * fmaxf(acc[mt][2][r] + bkb[2], 0.0f)
                         + qv[3] * fmaxf(acc[mt][3][r] + bkb[3], 0.0f);
                p0 += __shfl_xor(p0, 1);  p1 += __shfl_xor(p1, 1);
                p0 += __shfl_xor(p0, 2);  p1 += __shfl_xor(p1, 2);
                p0 += __shfl_xor(p0, 4);  p1 += __shfl_xor(p1, 4);
                p0 += __shfl_xor(p0, 8);  p1 += __shfl_xor(p1, 8);
                if (l15 == 0) {
                    const int t = mt * 16 + l4 * 4 + r;
                    s_att[w][0][t] = p0 * (1.0f / 3.0f);
                    s_att[w][1][t] = p1 * (1.0f / 3.0f);
                }
            }
    }
    __syncthreads();

    // ---- wave-parallel softmax (wave w handles its own 2 heads) ----
    {
        const int hsel = lane >> 5;          // which of my 2 heads
        const int tt   = lane & 31;          // t and t+32
        const float a0  = s_att[w][hsel][tt];
        const float a1v = s_att[w][hsel][tt + 32];
        const bool  v1  = (tt + 32) < HIS;
        float m = fmaxf(a0, v1 ? a1v : -1e30f);
        m = fmaxf(m, __shfl_xor(m, 1));
        m = fmaxf(m, __shfl_xor(m, 2));
        m = fmaxf(m, __shfl_xor(m, 4));
        m = fmaxf(m, __shfl_xor(m, 8));
        m = fmaxf(m, __shfl_xor(m, 16));
        const float e0 = expf(a0 - m);
        const float e1 = v1 ? expf(a1v - m) : 0.0f;
        float s = e0 + e1;
        s += __shfl_xor(s, 1);
        s += __shfl_xor(s, 2);
        s += __shfl_xor(s, 4);
        s += __shfl_xor(s, 8);
        s += __shfl_xor(s, 16);
        const float inv = 1.0f / s;
        s_att[w][hsel][tt]      = e0 * inv;
        s_att[w][hsel][tt + 32] = e1 * inv;
    }
    __syncthreads();

    // ---- pass 2: vh GEMM -> PV ----
    #pragma unroll
    for (int mt = 0; mt < 4; ++mt)
        #pragma unroll
        for (int nt = 0; nt < 4; ++nt) acc[mt][nt] = (f32x4)0.0f;

    #pragma unroll 2
    for (int kk = 0; kk < 8; ++kk) {
        half8 afr[4];
        #pragma unroll
        for (int mt = 0; mt < 3; ++mt)
            afr[mt] = *reinterpret_cast<const half8*>(
                &encF[(((fbase + kk) * 3 + mt) * 64 + lane) * 8]);
        afr[3] = (half8)(HALF)0.0f;
        if (l15 < 2)
            afr[3] = *reinterpret_cast<const half8*>(
                &enc2[((size_t)bidx * 2 + l15) * EDIM + kk * 32 + l4 * 8]);
        #pragma unroll
        for (int nt = 0; nt < 4; ++nt) {
            const half8 bfr = *reinterpret_cast<const half8*>(
                WvP + ((size_t)((w * 4 + nt) * 8 + kk) * 64 + lane) * 8);
            #pragma unroll
            for (int mt = 0; mt < 4; ++mt)
                acc[mt][nt] = __builtin_amdgcn_mfma_f32_16x16x32_f16(afr[mt], bfr, acc[mt][nt], 0, 0, 0);
        }
    }

    {
        float bvb[4];
        #pragma unroll
        for (int nt = 0; nt < 4; ++nt) bvb[nt] = bv[w * 64 + nt * 16 + l15];
        float o0 = 0.f, o1 = 0.f, o2 = 0.f, o3 = 0.f;
        #pragma unroll
        for (int mt = 0; mt < 4; ++mt)
            #pragma unroll
            for (int r = 0; r < 4; ++r) {
                const int t = mt * 16 + l4 * 4 + r;
                const float a0 = s_att[w][0][t];
                const float a1 = s_att[w][1][t];
                o0 += a0 * fmaxf(acc[mt][0][r] + bvb[0], 0.0f);
                o1 += a0 * fmaxf(acc[mt][1][r] + bvb[1], 0.0f);
                o2 += a1 * fmaxf(acc[mt][2][r] + bvb[2], 0.0f);
                o3 += a1 * fmaxf(acc[mt][3][r] + bvb[3], 0.0f);
            }
        o0 += __shfl_xor(o0, 16); o1 += __shfl_xor(o1, 16);
        o2 += __shfl_xor(o2, 16); o3 += __shfl_xor(o3, 16);
        o0 += __shfl_xor(o0, 32); o1 += __shfl_xor(o1, 32);
        o2 += __shfl_xor(o2, 32); o3 += __shfl_xor(o3, 32);
        if (lane < 16) {
            s_o[w * 64 +  0 + l15] = o0;
            s_o[w * 64 + 16 + l15] = o1;
            s_o[w * 64 + 32 + l15] = o2;
            s_o[w * 64 + 48 + l15] = o3;
        }
    }
    __syncthreads();

    // ---- out projection (4 accumulators) ----
    {
        const int e = tid;
        float a0 = bout[e], a1 = 0.f, a2 = 0.f, a3 = 0.f;
        #pragma unroll 4
        for (int j = 0; j < 32; ++j) {
            const half8 hv = *reinterpret_cast<const half8*>(&WoI[(j * EDIM + e) * 8]);
            const float4 v0 = *reinterpret_cast<const float4*>(&s_o[j * 8]);
            const float4 v1 = *reinterpret_cast<const float4*>(&s_o[j * 8 + 4]);
            a0 += v0.x * (float)hv[0] + v0.y * (float)hv[1];
            a1 += v0.z * (float)hv[2] + v0.w * (float)hv[3];
            a2 += v1.x * (float)hv[4] + v1.y * (float)hv[5];
            a3 += v1.z * (float)hv[6] + v1.w * (float)hv[7];
        }
        out[bidx * EDIM + e] = fmaxf((a0 + a1) + (a2 + a3), 0.0f);
    }
}

// ---------------- fallback fused kernel (round-2 structure) ----------------
__global__ __launch_bounds__(256) void mha_mfma(
    const float* __restrict__ q,
    const float* __restrict__ kin,
    const float* __restrict__ bq,
    const float* __restrict__ bk,
    const float* __restrict__ bv,
    const float* __restrict__ bout,
    const float* __restrict__ Wenc,
    const char*  __restrict__ ws,
    float* __restrict__ out)
{
    const int tid  = threadIdx.x;
    const int bidx = blockIdx.x;
    const int b = bidx >> 6;
    const int n = bidx & 63;
    const int lane = tid & 63;
    const int w    = tid >> 6;
    const int l15  = lane & 15;
    const int l4   = lane >> 4;

    const HALF*  WkP = (const HALF*)(ws + WS_WKP);
    const HALF*  WvP = (const HALF*)(ws + WS_WVP);
    const HALF*  WqI = (const HALF*)(ws + WS_WQI);
    const HALF*  WoI = (const HALF*)(ws + WS_WOI);
    const float* PE  = (const float*)(ws + WS_PE);
    const int*  idxT = (const int*)(ws + WS_IDX);

    __shared__ __align__(16) float s_q[EDIM];
    __shared__ __align__(16) float s_qh[EDIM];
    __shared__ __align__(16) float s_neigh[HIS][12];
    __shared__ __align__(16) HALF  s_enc[64 * EDIM];
    __shared__ float s_att[NV][64];
    __shared__ __align__(16) float s_o[EDIM];

    s_q[tid] = q[bidx * EDIM + tid];
    __syncthreads();

    for (int i = tid; i < HIS * 12; i += 256) {
        const int t = i / 12;
        const int d = i - t * 12;
        float val = 0.0f;
        if (d < DKA) val = kin[((b * HIS + t) * NA + idxT[n * HIS + t]) * DKA + d];
        s_neigh[t][d] = val;
    }
    __syncthreads();

    {
        const int e = tid;
        float acc = bq[e];
        #pragma unroll 4
        for (int j = 0; j < 32; ++j) {
            const half8 hv = *reinterpret_cast<const half8*>(&WqI[(j * EDIM + e) * 8]);
            const float4 q0 = *reinterpret_cast<const float4*>(&s_q[j * 8]);
            const float4 q1 = *reinterpret_cast<const float4*>(&s_q[j * 8 + 4]);
            acc += q0.x*(float)hv[0] + q0.y*(float)hv[1] + q0.z*(float)hv[2] + q0.w*(float)hv[3]
                 + q1.x*(float)hv[4] + q1.y*(float)hv[5] + q1.z*(float)hv[6] + q1.w*(float)hv[7];
        }
        s_qh[e] = fmaxf(acc, 0.0f);

        float we[12];
        #pragma unroll
        for (int j = 0; j < 12; ++j) we[j] = (j < DKA) ? Wenc[j * EDIM + e] : 0.0f;

        #pragma unroll 2
        for (int t = 0; t < HIS; ++t) {
            const float4 n0 = *reinterpret_cast<const float4*>(&s_neigh[t][0]);
            const float4 n1 = *reinterpret_cast<const float4*>(&s_neigh[t][4]);
            const float4 n2 = *reinterpret_cast<const float4*>(&s_neigh[t][8]);
            float x = n0.x*we[0] + n0.y*we[1] + n0.z*we[2] + n0.w*we[3]
                    + n1.x*we[4] + n1.y*we[5] + n1.z*we[6] + n1.w*we[7]
                    + n2.x*we[8];
            x = 0.5f * x * (1.0f + erff(x * 0.70710678118654752f));
            const float v = x + PE[t * EDIM + e];
            s_enc[t * EDIM + (((e >> 3) ^ (t & 7)) << 3) + (e & 7)] = (HALF)v;
        }
        #pragma unroll
        for (int t = HIS; t < 64; ++t)
            s_enc[t * EDIM + (((e >> 3) ^ (t & 7)) << 3) + (e & 7)] = (HALF)0.0f;
    }
    __syncthreads();

    f32x4 ka[4][4], va[4][4];
    #pragma unroll
    for (int mt = 0; mt < 4; ++mt)
        #pragma unroll
        for (int nt = 0; nt < 4; ++nt) { ka[mt][nt] = (f32x4)0.0f; va[mt][nt] = (f32x4)0.0f; }

    #pragma unroll 2
    for (int kk = 0; kk < 8; ++kk) {
        half8 afr[4];
        #pragma unroll
        for (int mt = 0; mt < 4; ++mt) {
            const int t  = mt * 16 + l15;
            const int g  = ((kk * 4 + l4)) ^ (t & 7);
            afr[mt] = *reinterpret_cast<const half8*>(&s_enc[t * EDIM + g * 8]);
        }
        #pragma unroll
        for (int nt = 0; nt < 4; ++nt) {
            const size_t off = ((size_t)((w * 4 + nt) * 8 + kk) * 64 + lane) * 8;
            const half8 bkfr = *reinterpret_cast<const half8*>(WkP + off);
            const half8 bvfr = *reinterpret_cast<const half8*>(WvP + off);
            #pragma unroll
            for (int mt = 0; mt < 4; ++mt) {
                ka[mt][nt] = __builtin_amdgcn_mfma_f32_16x16x32_f16(afr[mt], bkfr, ka[mt][nt], 0, 0, 0);
                va[mt][nt] = __builtin_amdgcn_mfma_f32_16x16x32_f16(afr[mt], bvfr, va[mt][nt], 0, 0, 0);
            }
        }
    }

    {
        float qv[4], bkb[4];
        #pragma unroll
        for (int nt = 0; nt < 4; ++nt) {
            const int col = w * 64 + nt * 16 + l15;
            qv[nt]  = s_qh[col];
            bkb[nt] = bk[col];
        }
        #pragma unroll
        for (int mt = 0; mt < 4; ++mt)
            #pragma unroll
            for (int r = 0; r < 4; ++r) {
                float p0 = qv[0] * fmaxf(ka[mt][0][r] + bkb[0], 0.0f)
                         + qv[1] * fmaxf(ka[mt][1][r] + bkb[1], 0.0f);
                float p1 = qv[2] * fmaxf(ka[mt][2][r] + bkb[2], 0.0f)
                         + qv[3] * fmaxf(ka[mt][3][r] + bkb[3], 0.0f);
                p0 += __shfl_xor(p0, 1);  p1 += __shfl_xor(p1, 1);
                p0 += __shfl_xor(p0, 2);  p1 += __shfl_xor(p1, 2);
                p0 += __shfl_xor(p0, 4);  p1 += __shfl_xor(p1, 4);
                p0 += __shfl_xor(p0, 8);  p1 += __shfl_xor(p1, 8);
                if (l15 == 0) {
                    const int t = mt * 16 + l4 * 4 + r;
                    s_att[2 * w][t]     = p0 * (1.0f / 3.0f);
                    s_att[2 * w + 1][t] = p1 * (1.0f / 3.0f);
                }
            }
    }
    __syncthreads();

    if (tid < NV) {
        float m = -1e30f;
        for (int t = 0; t < HIS; ++t) m = fmaxf(m, s_att[tid][t]);
        float ssum = 0.0f;
        for (int t = 0; t < HIS; ++t) {
            const float ex = expf(s_att[tid][t] - m);
            s_att[tid][t] = ex;
            ssum += ex;
        }
        const float inv = 1.0f / ssum;
        for (int t = 0; t < HIS; ++t) s_att[tid][t] *= inv;
        for (int t = HIS; t < 64; ++t) s_att[tid][t] = 0.0f;
    }
    __syncthreads();

    {
        float bvb[4];
        #pragma unroll
        for (int nt = 0; nt < 4; ++nt) bvb[nt] = bv[w * 64 + nt * 16 + l15];
        float o0 = 0.f, o1 = 0.f, o2 = 0.f, o3 = 0.f;
        #pragma unroll
        for (int mt = 0; mt < 4; ++mt)
            #pragma unroll
            for (int r = 0; r < 4; ++r) {
                const int t = mt * 16 + l4 * 4 + r;
                const float a0 = s_att[2 * w][t];
                const float a1 = s_att[2 * w + 1][t];
                o0 += a0 * fmaxf(va[mt][0][r] + bvb[0], 0.0f);
                o1 += a0 * fmaxf(va[mt][1][r] + bvb[1], 0.0f);
                o2 += a1 * fmaxf(va[mt][2][r] + bvb[2], 0.0f);
                o3 += a1 * fmaxf(va[mt][3][r] + bvb[3], 0.0f);
            }
        o0 += __shfl_xor(o0, 16); o1 += __shfl_xor(o1, 16);
        o2 += __shfl_xor(o2, 16); o3 += __shfl_xor(o3, 16);
        o0 += __shfl_xor(o0, 32); o1 += __shfl_xor(o1, 32);
        o2 += __shfl_xor(o2, 32); o3 += __shfl_xor(o3, 32);
        if (lane < 16) {
            s_o[w * 64 +  0 + l15] = o0;
            s_o[w * 64 + 16 + l15] = o1;
            s_o[w * 64 + 32 + l15] = o2;
            s_o[w * 64 + 48 + l15] = o3;
        }
    }
    __syncthreads();

    {
        const int e = tid;
        float acc = bout[e];
        #pragma unroll 4
        for (int j = 0; j < 32; ++j) {
            const half8 hv = *reinterpret_cast<const half8*>(&WoI[(j * EDIM + e) * 8]);
            const float4 o0 = *reinterpret_cast<const float4*>(&s_o[j * 8]);
            const float4 o1 = *reinterpret_cast<const float4*>(&s_o[j * 8 + 4]);
            acc += o0.x*(float)hv[0] + o0.y*(float)hv[1] + o0.z*(float)hv[2] + o0.w*(float)hv[3]
                 + o1.x*(float)hv[4] + o1.y*(float)hv[5] + o1.z*(float)hv[6] + o1.w*(float)hv[7];
        }
        out[bidx * EDIM + e] = fmaxf(acc, 0.0f);
    }
}

extern "C" void kernel_launch(void* const* d_in, const int* in_sizes, int n_in,
                              void* d_out, int out_size, void* d_ws, size_t ws_size,
                              hipStream_t stream) {
    const float* q    = (const float*)d_in[0];
    const float* kin  = (const float*)d_in[1];
    const float* adjs = (const float*)d_in[2];
    const float* Wq   = (const float*)d_in[3];
    const float* bq   = (const float*)d_in[4];
    const float* Wk   = (const float*)d_in[5];
    const float* bk   = (const float*)d_in[6];
    const float* Wv   = (const float*)d_in[7];
    const float* bv   = (const float*)d_in[8];
    const float* Wout = (const float*)d_in[9];
    const float* bout = (const float*)d_in[10];
    const float* Wenc = (const float*)d_in[11];
    float* out = (float*)d_out;
    char* ws = (char*)d_ws;

    hipLaunchKernelGGL(pack_setup, dim3(256), dim3(256), 0, stream,
                       Wk, Wv, Wq, Wout, adjs, ws);

    if (ws_size >= WS_NEED) {
        hipLaunchKernelGGL(enc_kernel, dim3(NB * NA), dim3(256), 0, stream,
                           q, kin, bq, Wenc, ws, ws);
        hipLaunchKernelGGL(attn_kernel, dim3(NB * NA), dim3(256), 0, stream,
                           bk, bv, bout, ws, out);
    } else {
        hipLaunchKernelGGL(mha_mfma, dim3(NB * NA), dim3(256), 0, stream,
                           q, kin, bq, bk, bv, bout, Wenc, ws, out);
    }
}

// Round 5
// 117.351 us; speedup vs baseline: 1.0941x; 1.0941x over previous
//
#include <hip/hip_runtime.h>
#include <math.h>

#define NB   32
#define NA   64
#define EDIM 256
#define HIS  50
#define DKA  9
#define NV   8

typedef _Float16 HALF;
typedef _Float16 half8 __attribute__((ext_vector_type(8)));
typedef float    f32x4 __attribute__((ext_vector_type(4)));

// ws layout (bytes) — total exactly 54,065,664 (known to fit):
#define WS_WKP   0          // f16 B-frag-packed Wk                  131072
#define WS_WVP   131072     // f16 B-frag-packed Wv                  131072
#define WS_WQP   262144     // f16 B-frag-packed Wq                  131072
#define WS_WOP   393216     // f16 B-frag-packed Wout                131072
#define WS_PE    524288     // f32 PE [50][256]                      51200
#define WS_IDX   575488     // int idxTab [64][50]                   12800
#define WS_QH    588288     // f16 [2048][256]: qh, then overwritten by O (per-row, safe)
#define WS_ENCF  1636864    // f16 A-frags [bidx][kk=8][mt=3][64][8] 50331648
#define WS_ENC2  51968512   // f16 rows t=48,49 [bidx][2][256]       2097152
#define WS_NEED  54065664ULL

// ---------------- setup: pack weights (B-fragment order), PE, adjacency ----------------
__global__ __launch_bounds__(256) void pack_setup(
    const float* __restrict__ Wk, const float* __restrict__ Wv,
    const float* __restrict__ Wq, const float* __restrict__ Wout,
    const float* __restrict__ adjs,
    char* __restrict__ ws)
{
    const int tid = blockIdx.x * 256 + threadIdx.x;   // 0..65535
    HALF* WkP  = (HALF*)(ws + WS_WKP);
    HALF* WvP  = (HALF*)(ws + WS_WVP);
    HALF* WqP  = (HALF*)(ws + WS_WQP);
    HALF* WoP  = (HALF*)(ws + WS_WOP);
    float* PE  = (float*)(ws + WS_PE);
    int*  idxT = (int*)(ws + WS_IDX);

    // B-fragment pack: out = ((ntile*8 + ktile)*64 + lane)*8 + elem
    {
        const int elem = tid & 7;
        const int lane = (tid >> 3) & 63;
        const int kt   = (tid >> 9) & 7;
        const int nt   = tid >> 12;
        const int k = kt * 32 + (lane >> 4) * 8 + elem;
        const int n = nt * 16 + (lane & 15);
        WkP[tid] = (HALF)Wk[k * EDIM + n];
        WvP[tid] = (HALF)Wv[k * EDIM + n];
        WqP[tid] = (HALF)Wq[k * EDIM + n];
        WoP[tid] = (HALF)Wout[k * EDIM + n];
    }
    // positional encoding table
    if (tid < HIS * EDIM) {
        const int t = tid >> 8;
        const int e = tid & 255;
        const float dt = expf(-(float)(e & ~1) * (9.210340371976184f / 256.0f));
        const float arg = (float)t * dt;
        PE[tid] = (e & 1) ? cosf(arg) : sinf(arg);
    }
    // adjacency one-hot -> index
    if (tid < NA * HIS) {
        const float* row = adjs + tid * NA;   // tid = n*HIS + t
        int best = 0;
        #pragma unroll
        for (int a = 0; a < NA; ++a) best = (row[a] > 0.5f) ? a : best;
        idxT[tid] = best;
    }
}

// ---------------- qh GEMM: qh = relu(q @ Wq + bq), f16 out ----------------
__global__ __launch_bounds__(256) void qh_gemm(
    const float* __restrict__ q,
    const float* __restrict__ bq,
    const char*  __restrict__ ws,
    char* __restrict__ wsout)
{
    const int tid = threadIdx.x, lane = tid & 63, w = tid >> 6;
    const int l15 = lane & 15, l4 = lane >> 4;
    const int r0  = blockIdx.x * 64;
    const HALF* WqP = (const HALF*)(ws + WS_WQP);
    HALF* qh = (HALF*)(wsout + WS_QH);

    f32x4 acc[4][4];
    #pragma unroll
    for (int mt = 0; mt < 4; ++mt)
        #pragma unroll
        for (int nt = 0; nt < 4; ++nt) acc[mt][nt] = (f32x4)0.0f;

    #pragma unroll 2
    for (int kk = 0; kk < 8; ++kk) {
        half8 afr[4];
        #pragma unroll
        for (int mt = 0; mt < 4; ++mt) {
            const float* ap = &q[(size_t)(r0 + mt * 16 + l15) * EDIM + kk * 32 + l4 * 8];
            const float4 a0 = *reinterpret_cast<const float4*>(ap);
            const float4 a1 = *reinterpret_cast<const float4*>(ap + 4);
            half8 h;
            h[0] = (HALF)a0.x; h[1] = (HALF)a0.y; h[2] = (HALF)a0.z; h[3] = (HALF)a0.w;
            h[4] = (HALF)a1.x; h[5] = (HALF)a1.y; h[6] = (HALF)a1.z; h[7] = (HALF)a1.w;
            afr[mt] = h;
        }
        #pragma unroll
        for (int nt = 0; nt < 4; ++nt) {
            const half8 bfr = *reinterpret_cast<const half8*>(
                WqP + ((size_t)((w * 4 + nt) * 8 + kk) * 64 + lane) * 8);
            #pragma unroll
            for (int mt = 0; mt < 4; ++mt)
                acc[mt][nt] = __builtin_amdgcn_mfma_f32_16x16x32_f16(afr[mt], bfr, acc[mt][nt], 0, 0, 0);
        }
    }

    float bqa[4];
    #pragma unroll
    for (int nt = 0; nt < 4; ++nt) bqa[nt] = bq[w * 64 + nt * 16 + l15];
    #pragma unroll
    for (int mt = 0; mt < 4; ++mt)
        #pragma unroll
        for (int nt = 0; nt < 4; ++nt)
            #pragma unroll
            for (int r = 0; r < 4; ++r) {
                const int row = l4 * 4 + r;
                qh[(size_t)(r0 + mt * 16 + row) * EDIM + w * 64 + nt * 16 + l15] =
                    (HALF)fmaxf(acc[mt][nt][r] + bqa[nt], 0.0f);
            }
}

// ---------------- out GEMM: out = relu(O @ Wout + bout), f32 out ----------------
__global__ __launch_bounds__(256) void out_gemm(
    const float* __restrict__ bout,
    const char*  __restrict__ ws,
    float* __restrict__ out)
{
    const int tid = threadIdx.x, lane = tid & 63, w = tid >> 6;
    const int l15 = lane & 15, l4 = lane >> 4;
    const int r0  = blockIdx.x * 64;
    const HALF* WoP = (const HALF*)(ws + WS_WOP);
    const HALF* O   = (const HALF*)(ws + WS_QH);   // attn overwrote qh rows with o

    f32x4 acc[4][4];
    #pragma unroll
    for (int mt = 0; mt < 4; ++mt)
        #pragma unroll
        for (int nt = 0; nt < 4; ++nt) acc[mt][nt] = (f32x4)0.0f;

    #pragma unroll 2
    for (int kk = 0; kk < 8; ++kk) {
        half8 afr[4];
        #pragma unroll
        for (int mt = 0; mt < 4; ++mt)
            afr[mt] = *reinterpret_cast<const half8*>(
                &O[(size_t)(r0 + mt * 16 + l15) * EDIM + kk * 32 + l4 * 8]);
        #pragma unroll
        for (int nt = 0; nt < 4; ++nt) {
            const half8 bfr = *reinterpret_cast<const half8*>(
                WoP + ((size_t)((w * 4 + nt) * 8 + kk) * 64 + lane) * 8);
            #pragma unroll
            for (int mt = 0; mt < 4; ++mt)
                acc[mt][nt] = __builtin_amdgcn_mfma_f32_16x16x32_f16(afr[mt], bfr, acc[mt][nt], 0, 0, 0);
        }
    }

    float boa[4];
    #pragma unroll
    for (int nt = 0; nt < 4; ++nt) boa[nt] = bout[w * 64 + nt * 16 + l15];
    #pragma unroll
    for (int mt = 0; mt < 4; ++mt)
        #pragma unroll
        for (int nt = 0; nt < 4; ++nt)
            #pragma unroll
            for (int r = 0; r < 4; ++r) {
                const int row = l4 * 4 + r;
                out[(size_t)(r0 + mt * 16 + row) * EDIM + w * 64 + nt * 16 + l15] =
                    fmaxf(acc[mt][nt][r] + boa[nt], 0.0f);
            }
}

// ---------------- K1: enc in A-fragment order, all (b,n) ----------------
__global__ __launch_bounds__(256) void enc_kernel2(
    const float* __restrict__ kin,
    const float* __restrict__ Wenc,
    const char*  __restrict__ ws,
    char* __restrict__ wsout)
{
    const int tid  = threadIdx.x;
    const int bidx = blockIdx.x;
    const int b = bidx >> 6;
    const int n = bidx & 63;
    const int lane = tid & 63;
    const int w    = tid >> 6;

    const float* PE = (const float*)(ws + WS_PE);
    const int* idxT = (const int*)(ws + WS_IDX);
    HALF* encF = (HALF*)(wsout + WS_ENCF);
    HALF* enc2 = (HALF*)(wsout + WS_ENC2);

    __shared__ __align__(16) float s_neigh[HIS][12];

    for (int i = tid; i < HIS * 12; i += 256) {
        const int t = i / 12;
        const int d = i - t * 12;
        float val = 0.0f;
        if (d < DKA) val = kin[((b * HIS + t) * NA + idxT[n * HIS + t]) * DKA + d];
        s_neigh[t][d] = val;
    }
    __syncthreads();

    const int L  = lane & 31;
    const int th = lane >> 5;
    const int e0 = L * 8;
    float4 weA[DKA], weB[DKA];
    #pragma unroll
    for (int d = 0; d < DKA; ++d) {
        weA[d] = *reinterpret_cast<const float4*>(&Wenc[d * EDIM + e0]);
        weB[d] = *reinterpret_cast<const float4*>(&Wenc[d * EDIM + e0 + 4]);
    }

    for (int tp = w; tp < 25; tp += 4) {
        const int t = 2 * tp + th;      // 0..49
        float nv[DKA];
        #pragma unroll
        for (int d = 0; d < DKA; ++d) nv[d] = s_neigh[t][d];
        float4 xA = nv[0] * weA[0];
        float4 xB = nv[0] * weB[0];
        #pragma unroll
        for (int d = 1; d < DKA; ++d) { xA += nv[d] * weA[d]; xB += nv[d] * weB[d]; }
        const float4 peA = *reinterpret_cast<const float4*>(&PE[t * EDIM + e0]);
        const float4 peB = *reinterpret_cast<const float4*>(&PE[t * EDIM + e0 + 4]);
        float r0 = 0.5f * xA.x * (1.0f + erff(xA.x * 0.70710678118654752f)) + peA.x;
        float r1 = 0.5f * xA.y * (1.0f + erff(xA.y * 0.70710678118654752f)) + peA.y;
        float r2 = 0.5f * xA.z * (1.0f + erff(xA.z * 0.70710678118654752f)) + peA.z;
        float r3 = 0.5f * xA.w * (1.0f + erff(xA.w * 0.70710678118654752f)) + peA.w;
        float r4 = 0.5f * xB.x * (1.0f + erff(xB.x * 0.70710678118654752f)) + peB.x;
        float r5 = 0.5f * xB.y * (1.0f + erff(xB.y * 0.70710678118654752f)) + peB.y;
        float r6 = 0.5f * xB.z * (1.0f + erff(xB.z * 0.70710678118654752f)) + peB.z;
        float r7 = 0.5f * xB.w * (1.0f + erff(xB.w * 0.70710678118654752f)) + peB.w;
        half8 hv;
        hv[0] = (HALF)r0; hv[1] = (HALF)r1; hv[2] = (HALF)r2; hv[3] = (HALF)r3;
        hv[4] = (HALF)r4; hv[5] = (HALF)r5; hv[6] = (HALF)r6; hv[7] = (HALF)r7;
        if (t < 48) {
            const int kk = L >> 2;
            const int mt = t >> 4;
            const int fl = (L & 3) * 16 + (t & 15);
            const size_t off = ((((size_t)bidx * 8 + kk) * 3 + mt) * 64 + fl) * 8;
            *reinterpret_cast<half8*>(&encF[off]) = hv;
        } else {
            const size_t off = (((size_t)bidx * 2 + (t - 48)) * EDIM) + e0;
            *reinterpret_cast<half8*>(&enc2[off]) = hv;
        }
    }
}

// ---------------- K2: attention per (b,n) — single-pass dual GEMM ----------------
__global__ __launch_bounds__(256) void attn_kernel(
    const float* __restrict__ bk,
    const float* __restrict__ bv,
    const char*  __restrict__ ws,
    char* __restrict__ wsout)
{
    const int tid  = threadIdx.x;
    const int bidx = blockIdx.x;
    const int lane = tid & 63;
    const int w    = tid >> 6;
    const int l15  = lane & 15;
    const int l4   = lane >> 4;

    const HALF* WkP  = (const HALF*)(ws + WS_WKP);
    const HALF* WvP  = (const HALF*)(ws + WS_WVP);
    const HALF* qh   = (const HALF*)(ws + WS_QH);
    const HALF* encF = (const HALF*)(ws + WS_ENCF);
    const HALF* enc2 = (const HALF*)(ws + WS_ENC2);
    HALF* O = (HALF*)(wsout + WS_QH);   // overwrite own qh row at the end (safe per-row)

    __shared__ float s_att[4][2][64];
    __shared__ __align__(16) float s_o[EDIM];

    float qv[4], bkb[4], bvb[4];
    #pragma unroll
    for (int nt = 0; nt < 4; ++nt) {
        const int col = w * 64 + nt * 16 + l15;
        qv[nt]  = (float)qh[(size_t)bidx * EDIM + col];
        bkb[nt] = bk[col];
        bvb[nt] = bv[col];
    }

    f32x4 ka[4][4], va[4][4];
    #pragma unroll
    for (int mt = 0; mt < 4; ++mt)
        #pragma unroll
        for (int nt = 0; nt < 4; ++nt) { ka[mt][nt] = (f32x4)0.0f; va[mt][nt] = (f32x4)0.0f; }

    const size_t fbase = (size_t)bidx * 8;
    auto loadA = [&](half8* dst, int kk) {
        #pragma unroll
        for (int mt = 0; mt < 3; ++mt)
            dst[mt] = *reinterpret_cast<const half8*>(
                &encF[(((fbase + kk) * 3 + mt) * 64 + lane) * 8]);
        half8 z = (half8)(HALF)0.0f;
        if (l15 < 2)
            z = *reinterpret_cast<const half8*>(
                &enc2[((size_t)bidx * 2 + l15) * EDIM + kk * 32 + l4 * 8]);
        dst[3] = z;
    };

    half8 abuf[2][4];
    loadA(abuf[0], 0);
    #pragma unroll
    for (int kk = 0; kk < 8; ++kk) {
        const int c = kk & 1;                      // compile-time after full unroll
        if (kk < 7) loadA(abuf[c ^ 1], kk + 1);    // prefetch next kk's A-frags
        #pragma unroll
        for (int nt = 0; nt < 4; ++nt) {
            const size_t boff = ((size_t)((w * 4 + nt) * 8 + kk) * 64 + lane) * 8;
            const half8 bkfr = *reinterpret_cast<const half8*>(WkP + boff);
            const half8 bvfr = *reinterpret_cast<const half8*>(WvP + boff);
            #pragma unroll
            for (int mt = 0; mt < 4; ++mt) {
                ka[mt][nt] = __builtin_amdgcn_mfma_f32_16x16x32_f16(abuf[c][mt], bkfr, ka[mt][nt], 0, 0, 0);
                va[mt][nt] = __builtin_amdgcn_mfma_f32_16x16x32_f16(abuf[c][mt], bvfr, va[mt][nt], 0, 0, 0);
            }
        }
    }

    // ---- logits: relu(kh+bk) · qh, 16-lane shfl reduce ----
    #pragma unroll
    for (int mt = 0; mt < 4; ++mt)
        #pragma unroll
        for (int r = 0; r < 4; ++r) {
            float p0 = qv[0] * fmaxf(ka[mt][0][r] + bkb[0], 0.0f)
                     + qv[1] * fmaxf(ka[mt][1][r] + bkb[1], 0.0f);
            float p1 = qv[2] * fmaxf(ka[mt][2][r] + bkb[2], 0.0f)
                     + qv[3] * fmaxf(ka[mt][3][r] + bkb[3], 0.0f);
            p0 += __shfl_xor(p0, 1);  p1 += __shfl_xor(p1, 1);
            p0 += __shfl_xor(p0, 2);  p1 += __shfl_xor(p1, 2);
            p0 += __shfl_xor(p0, 4);  p1 += __shfl_xor(p1, 4);
            p0 += __shfl_xor(p0, 8);  p1 += __shfl_xor(p1, 8);
            if (l15 == 0) {
                const int t = mt * 16 + l4 * 4 + r;
                s_att[w][0][t] = p0 * (1.0f / 3.0f);
                s_att[w][1][t] = p1 * (1.0f / 3.0f);
            }
        }
    __syncthreads();

    // ---- wave-parallel softmax (wave w owns its own 2 heads) ----
    {
        const int hsel = lane >> 5;
        const int tt   = lane & 31;
        const float a0  = s_att[w][hsel][tt];
        const float a1v = s_att[w][hsel][tt + 32];
        const bool  v1  = (tt + 32) < HIS;
        float m = fmaxf(a0, v1 ? a1v : -1e30f);
        m = fmaxf(m, __shfl_xor(m, 1));
        m = fmaxf(m, __shfl_xor(m, 2));
        m = fmaxf(m, __shfl_xor(m, 4));
        m = fmaxf(m, __shfl_xor(m, 8));
        m = fmaxf(m, __shfl_xor(m, 16));
        const float e0 = expf(a0 - m);
        const float e1 = v1 ? expf(a1v - m) : 0.0f;
        float s = e0 + e1;
        s += __shfl_xor(s, 1);
        s += __shfl_xor(s, 2);
        s += __shfl_xor(s, 4);
        s += __shfl_xor(s, 8);
        s += __shfl_xor(s, 16);
        const float inv = 1.0f / s;
        s_att[w][hsel][tt]      = e0 * inv;
        s_att[w][hsel][tt + 32] = e1 * inv;
    }
    __syncthreads();

    // ---- PV from va ----
    {
        float o0 = 0.f, o1 = 0.f, o2 = 0.f, o3 = 0.f;
        #pragma unroll
        for (int mt = 0; mt < 4; ++mt)
            #pragma unroll
            for (int r = 0; r < 4; ++r) {
                const int t = mt * 16 + l4 * 4 + r;
                const float a0 = s_att[w][0][t];
                const float a1 = s_att[w][1][t];
                o0 += a0 * fmaxf(va[mt][0][r] + bvb[0], 0.0f);
                o1 += a0 * fmaxf(va[mt][1][r] + bvb[1], 0.0f);
                o2 += a1 * fmaxf(va[mt][2][r] + bvb[2], 0.0f);
                o3 += a1 * fmaxf(va[mt][3][r] + bvb[3], 0.0f);
            }
        o0 += __shfl_xor(o0, 16); o1 += __shfl_xor(o1, 16);
        o2 += __shfl_xor(o2, 16); o3 += __shfl_xor(o3, 16);
        o0 += __shfl_xor(o0, 32); o1 += __shfl_xor(o1, 32);
        o2 += __shfl_xor(o2, 32); o3 += __shfl_xor(o3, 32);
        if (lane < 16) {
            s_o[w * 64 +  0 + l15] = o0;
            s_o[w * 64 + 16 + l15] = o1;
            s_o[w * 64 + 32 + l15] = o2;
            s_o[w * 64 + 48 + l15] = o3;
        }
    }
    __syncthreads();

    // ---- write O row (f16) for out_gemm ----
    O[(size_t)bidx * EDIM + tid] = (HALF)s_o[tid];
}

// ---------------- fallback (ws too small; f32 path, round-1 structure) ----------------
__global__ __launch_bounds__(256) void mha_fallback(
    const float* __restrict__ q,
    const float* __restrict__ kin,
    const float* __restrict__ adjs,
    const float* __restrict__ Wq, const float* __restrict__ bq,
    const float* __restrict__ Wk, const float* __restrict__ bk,
    const float* __restrict__ Wv, const float* __restrict__ bv,
    const float* __restrict__ Wout, const float* __restrict__ bout,
    const float* __restrict__ Wenc,
    float* __restrict__ out)
{
    const int tid  = threadIdx.x;
    const int bidx = blockIdx.x;
    const int b = bidx >> 6;
    const int n = bidx & 63;

    __shared__ __align__(16) float s_q[EDIM];
    __shared__ __align__(16) float s_qh[EDIM];
    __shared__ __align__(16) float s_neigh[HIS][12];
    __shared__ __align__(16) float s_enc[HIS * EDIM];
    __shared__ float s_att[NV][66];
    __shared__ __align__(16) float s_opart[4][EDIM];
    __shared__ __align__(16) float s_o[EDIM];
    __shared__ int s_idx[HIS];

    s_q[tid] = q[bidx * EDIM + tid];
    if (tid < HIS) {
        const float* row = adjs + (n * HIS + tid) * NA;
        int best = 0;
        #pragma unroll
        for (int a = 0; a < NA; ++a) best = (row[a] > 0.5f) ? a : best;
        s_idx[tid] = best;
    }
    __syncthreads();

    for (int i = tid; i < HIS * 12; i += 256) {
        const int t = i / 12;
        const int d = i - t * 12;
        float val = 0.0f;
        if (d < DKA) val = kin[((b * HIS + t) * NA + s_idx[t]) * DKA + d];
        s_neigh[t][d] = val;
    }
    __syncthreads();

    {
        const int e = tid;
        float acc = bq[e];
        #pragma unroll 4
        for (int d0 = 0; d0 < EDIM; d0 += 4) {
            const float4 qv = *reinterpret_cast<const float4*>(&s_q[d0]);
            acc += qv.x * Wq[(d0 + 0) * EDIM + e];
            acc += qv.y * Wq[(d0 + 1) * EDIM + e];
            acc += qv.z * Wq[(d0 + 2) * EDIM + e];
            acc += qv.w * Wq[(d0 + 3) * EDIM + e];
        }
        s_qh[e] = fmaxf(acc, 0.0f);

        float we[12];
        #pragma unroll
        for (int j = 0; j < 12; ++j) we[j] = (j < DKA) ? Wenc[j * EDIM + e] : 0.0f;
        const float dt = expf(-(float)(e & ~1) * (9.210340371976184f / 256.0f));
        for (int t = 0; t < HIS; ++t) {
            const float4 n0 = *reinterpret_cast<const float4*>(&s_neigh[t][0]);
            const float4 n1 = *reinterpret_cast<const float4*>(&s_neigh[t][4]);
            const float4 n2 = *reinterpret_cast<const float4*>(&s_neigh[t][8]);
            float x = n0.x*we[0] + n0.y*we[1] + n0.z*we[2] + n0.w*we[3]
                    + n1.x*we[4] + n1.y*we[5] + n1.z*we[6] + n1.w*we[7]
                    + n2.x*we[8];
            x = 0.5f * x * (1.0f + erff(x * 0.70710678118654752f));
            const float arg = (float)t * dt;
            const float pe = (e & 1) ? cosf(arg) : sinf(arg);
            s_enc[t * EDIM + e] = x + pe;
        }
    }
    __syncthreads();

    const int g = tid & 63;
    const int h = tid >> 6;
    const int tbase  = (h == 0) ? 0 : (h == 1) ? 13 : (h == 2) ? 25 : 37;
    const int tcount = (h == 1 || h == 2) ? 12 : 13;
    const int v = g >> 3;

    {
        float4 kacc[13];
        const float4 bkv = *reinterpret_cast<const float4*>(&bk[4 * g]);
        #pragma unroll
        for (int tt = 0; tt < 13; ++tt) kacc[tt] = bkv;
        #pragma unroll 2
        for (int d0 = 0; d0 < EDIM; d0 += 4) {
            const float4 w0 = *reinterpret_cast<const float4*>(&Wk[(d0 + 0) * EDIM + 4 * g]);
            const float4 w1 = *reinterpret_cast<const float4*>(&Wk[(d0 + 1) * EDIM + 4 * g]);
            const float4 w2 = *reinterpret_cast<const float4*>(&Wk[(d0 + 2) * EDIM + 4 * g]);
            const float4 w3 = *reinterpret_cast<const float4*>(&Wk[(d0 + 3) * EDIM + 4 * g]);
            #pragma unroll
            for (int tt = 0; tt < 13; ++tt) {
                const float4 ev = *reinterpret_cast<const float4*>(&s_enc[(tbase + tt) * EDIM + d0]);
                kacc[tt].x += ev.x * w0.x + ev.y * w1.x + ev.z * w2.x + ev.w * w3.x;
                kacc[tt].y += ev.x * w0.y + ev.y * w1.y + ev.z * w2.y + ev.w * w3.y;
                kacc[tt].z += ev.x * w0.z + ev.y * w1.z + ev.z * w2.z + ev.w * w3.z;
                kacc[tt].w += ev.x * w0.w + ev.y * w1.w + ev.z * w2.w + ev.w * w3.w;
            }
        }
        const float4 qv = *reinterpret_cast<const float4*>(&s_qh[4 * g]);
        #pragma unroll
        for (int tt = 0; tt < 13; ++tt) {
            float p = qv.x * fmaxf(kacc[tt].x, 0.0f)
                    + qv.y * fmaxf(kacc[tt].y, 0.0f)
                    + qv.z * fmaxf(kacc[tt].z, 0.0f)
                    + qv.w * fmaxf(kacc[tt].w, 0.0f);
            p += __shfl_xor(p, 1);
            p += __shfl_xor(p, 2);
            p += __shfl_xor(p, 4);
            if ((g & 7) == 0) s_att[v][tbase + tt] = p * (1.0f / 3.0f);
        }
    }
    __syncthreads();

    if (tid < NV) {
        float m = -1e30f;
        for (int t = 0; t < HIS; ++t) m = fmaxf(m, s_att[tid][t]);
        float ssum = 0.0f;
        for (int t = 0; t < HIS; ++t) {
            const float ex = expf(s_att[tid][t] - m);
            s_att[tid][t] = ex;
            ssum += ex;
        }
        const float inv = 1.0f / ssum;
        for (int t = 0; t < HIS; ++t) s_att[tid][t] *= inv;
    }
    __syncthreads();

    {
        float4 vacc[13];
        const float4 bvv = *reinterpret_cast<const float4*>(&bv[4 * g]);
        #pragma unroll
        for (int tt = 0; tt < 13; ++tt) vacc[tt] = bvv;
        #pragma unroll 2
        for (int d0 = 0; d0 < EDIM; d0 += 4) {
            const float4 w0 = *reinterpret_cast<const float4*>(&Wv[(d0 + 0) * EDIM + 4 * g]);
            const float4 w1 = *reinterpret_cast<const float4*>(&Wv[(d0 + 1) * EDIM + 4 * g]);
            const float4 w2 = *reinterpret_cast<const float4*>(&Wv[(d0 + 2) * EDIM + 4 * g]);
            const float4 w3 = *reinterpret_cast<const float4*>(&Wv[(d0 + 3) * EDIM + 4 * g]);
            #pragma unroll
            for (int tt = 0; tt < 13; ++tt) {
                const float4 ev = *reinterpret_cast<const float4*>(&s_enc[(tbase + tt) * EDIM + d0]);
                vacc[tt].x += ev.x * w0.x + ev.y * w1.x + ev.z * w2.x + ev.w * w3.x;
                vacc[tt].y += ev.x * w0.y + ev.y * w1.y + ev.z * w2.y + ev.w * w3.y;
                vacc[tt].z += ev.x * w0.z + ev.y * w1.z + ev.z * w2.z + ev.w * w3.z;
                vacc[tt].w += ev.x * w0.w + ev.y * w1.w + ev.z * w2.w + ev.w * w3.w;
            }
        }
        float4 po = make_float4(0.0f, 0.0f, 0.0f, 0.0f);
        #pragma unroll
        for (int tt = 0; tt < 13; ++tt) {
            if (tt < tcount) {
                const float a = s_att[v][tbase + tt];
                po.x += a * fmaxf(vacc[tt].x, 0.0f);
                po.y += a * fmaxf(vacc[tt].y, 0.0f);
                po.z += a * fmaxf(vacc[tt].z, 0.0f);
                po.w += a * fmaxf(vacc[tt].w, 0.0f);
            }
        }
        *reinterpret_cast<float4*>(&s_opart[h][4 * g]) = po;
    }
    __syncthreads();

    s_o[tid] = s_opart[0][tid] + s_opart[1][tid] + s_opart[2][tid] + s_opart[3][tid];
    __syncthreads();

    {
        const int e = tid;
        float acc = bout[e];
        #pragma unroll 4
        for (int d0 = 0; d0 < EDIM; d0 += 4) {
            const float4 ov = *reinterpret_cast<const float4*>(&s_o[d0]);
            acc += ov.x * Wout[(d0 + 0) * EDIM + e];
            acc += ov.y * Wout[(d0 + 1) * EDIM + e];
            acc += ov.z * Wout[(d0 + 2) * EDIM + e];
            acc += ov.w * Wout[(d0 + 3) * EDIM + e];
        }
        out[bidx * EDIM + e] = fmaxf(acc, 0.0f);
    }
}

extern "C" void kernel_launch(void* const* d_in, const int* in_sizes, int n_in,
                              void* d_out, int out_size, void* d_ws, size_t ws_size,
                              hipStream_t stream) {
    const float* q    = (const float*)d_in[0];
    const float* kin  = (const float*)d_in[1];
    const float* adjs = (const float*)d_in[2];
    const float* Wq   = (const float*)d_in[3];
    const float* bq   = (const float*)d_in[4];
    const float* Wk   = (const float*)d_in[5];
    const float* bk   = (const float*)d_in[6];
    const float* Wv   = (const float*)d_in[7];
    const float* bv   = (const float*)d_in[8];
    const float* Wout = (const float*)d_in[9];
    const float* bout = (const float*)d_in[10];
    const float* Wenc = (const float*)d_in[11];
    float* out = (float*)d_out;
    char* ws = (char*)d_ws;

    if (ws_size >= WS_NEED) {
        hipLaunchKernelGGL(pack_setup, dim3(256), dim3(256), 0, stream,
                           Wk, Wv, Wq, Wout, adjs, ws);
        hipLaunchKernelGGL(qh_gemm, dim3(NB * NA / 64), dim3(256), 0, stream,
                           q, bq, ws, ws);
        hipLaunchKernelGGL(enc_kernel2, dim3(NB * NA), dim3(256), 0, stream,
                           kin, Wenc, ws, ws);
        hipLaunchKernelGGL(attn_kernel, dim3(NB * NA), dim3(256), 0, stream,
                           bk, bv, ws, ws);
        hipLaunchKernelGGL(out_gemm, dim3(NB * NA / 64), dim3(256), 0, stream,
                           bout, ws, out);
    } else {
        hipLaunchKernelGGL(mha_fallback, dim3(NB * NA), dim3(256), 0, stream,
                           q, kin, adjs, Wq, bq, Wk, bk, Wv, bv, Wout, bout, Wenc, out);
    }
}

// Round 6
// 109.456 us; speedup vs baseline: 1.1731x; 1.0721x over previous
//
#include <hip/hip_runtime.h>
#include <math.h>

#define NB   32
#define NA   64
#define EDIM 256
#define HIS  50
#define DKA  9
#define NV   8

typedef _Float16 HALF;
typedef _Float16 half8 __attribute__((ext_vector_type(8)));
typedef float    f32x4 __attribute__((ext_vector_type(4)));

// ws layout (bytes) — total exactly 54,065,664 (known to fit):
#define WS_WKP   0          // f16 B-frag-packed Wk                  131072
#define WS_WVP   131072     // f16 B-frag-packed Wv                  131072
#define WS_WQP   262144     // f16 B-frag-packed Wq                  131072
#define WS_WOP   393216     // f16 B-frag-packed Wout                131072
#define WS_PE    524288     // f32 PE [50][256]                      51200
#define WS_IDX   575488     // int idxTab [64][50]                   12800
#define WS_QH    588288     // f16 [2048][256]: qh, then overwritten by O (per-row, safe)
#define WS_ENCF  1636864    // f16 A-frags [bidx][kk=8][mt=3][64][8] 50331648
#define WS_ENC2  51968512   // f16 rows t=48,49 [bidx][2][256]       2097152
#define WS_NEED  54065664ULL

// ---------------- setup: pack weights (B-fragment order), PE, adjacency ----------------
__global__ __launch_bounds__(256) void pack_setup(
    const float* __restrict__ Wk, const float* __restrict__ Wv,
    const float* __restrict__ Wq, const float* __restrict__ Wout,
    const float* __restrict__ adjs,
    char* __restrict__ ws)
{
    const int tid = blockIdx.x * 256 + threadIdx.x;   // 0..65535
    HALF* WkP  = (HALF*)(ws + WS_WKP);
    HALF* WvP  = (HALF*)(ws + WS_WVP);
    HALF* WqP  = (HALF*)(ws + WS_WQP);
    HALF* WoP  = (HALF*)(ws + WS_WOP);
    float* PE  = (float*)(ws + WS_PE);
    int*  idxT = (int*)(ws + WS_IDX);

    // B-fragment pack: out = ((ntile*8 + ktile)*64 + lane)*8 + elem
    {
        const int elem = tid & 7;
        const int lane = (tid >> 3) & 63;
        const int kt   = (tid >> 9) & 7;
        const int nt   = tid >> 12;
        const int k = kt * 32 + (lane >> 4) * 8 + elem;
        const int n = nt * 16 + (lane & 15);
        WkP[tid] = (HALF)Wk[k * EDIM + n];
        WvP[tid] = (HALF)Wv[k * EDIM + n];
        WqP[tid] = (HALF)Wq[k * EDIM + n];
        WoP[tid] = (HALF)Wout[k * EDIM + n];
    }
    // positional encoding table
    if (tid < HIS * EDIM) {
        const int t = tid >> 8;
        const int e = tid & 255;
        const float dt = expf(-(float)(e & ~1) * (9.210340371976184f / 256.0f));
        const float arg = (float)t * dt;
        PE[tid] = (e & 1) ? cosf(arg) : sinf(arg);
    }
    // adjacency one-hot -> index
    if (tid < NA * HIS) {
        const float* row = adjs + tid * NA;   // tid = n*HIS + t
        int best = 0;
        #pragma unroll
        for (int a = 0; a < NA; ++a) best = (row[a] > 0.5f) ? a : best;
        idxT[tid] = best;
    }
}

// ---------------- K1: enc (blocks 0..2047) + qh GEMM (blocks 2048..2111) ----------------
__global__ __launch_bounds__(256) void enc_qh(
    const float* __restrict__ q,
    const float* __restrict__ kin,
    const float* __restrict__ bq,
    const float* __restrict__ Wenc,
    const char*  __restrict__ ws,
    char* __restrict__ wsout)
{
    const int tid  = threadIdx.x;
    const int lane = tid & 63;
    const int w    = tid >> 6;

    __shared__ __align__(16) float s_neigh[HIS][12];

    if (blockIdx.x >= NB * NA) {
        // ======== qh GEMM tile: M=64, N=128 (grid 64 tiles) ========
        const int bx = blockIdx.x - NB * NA;     // 0..63
        const int r0 = (bx >> 1) * 64;
        const int nh = bx & 1;
        const int l15 = lane & 15, l4 = lane >> 4;
        const HALF* WqP = (const HALF*)(ws + WS_WQP);
        HALF* qh = (HALF*)(wsout + WS_QH);

        f32x4 acc[4][2];
        #pragma unroll
        for (int mt = 0; mt < 4; ++mt)
            #pragma unroll
            for (int nt = 0; nt < 2; ++nt) acc[mt][nt] = (f32x4)0.0f;

        #pragma unroll 2
        for (int kk = 0; kk < 8; ++kk) {
            half8 afr[4];
            #pragma unroll
            for (int mt = 0; mt < 4; ++mt) {
                const float* ap = &q[(size_t)(r0 + mt * 16 + l15) * EDIM + kk * 32 + l4 * 8];
                const float4 a0 = *reinterpret_cast<const float4*>(ap);
                const float4 a1 = *reinterpret_cast<const float4*>(ap + 4);
                half8 h;
                h[0] = (HALF)a0.x; h[1] = (HALF)a0.y; h[2] = (HALF)a0.z; h[3] = (HALF)a0.w;
                h[4] = (HALF)a1.x; h[5] = (HALF)a1.y; h[6] = (HALF)a1.z; h[7] = (HALF)a1.w;
                afr[mt] = h;
            }
            #pragma unroll
            for (int nt = 0; nt < 2; ++nt) {
                const int ntile = nh * 8 + w * 2 + nt;
                const half8 bfr = *reinterpret_cast<const half8*>(
                    WqP + ((size_t)(ntile * 8 + kk) * 64 + lane) * 8);
                #pragma unroll
                for (int mt = 0; mt < 4; ++mt)
                    acc[mt][nt] = __builtin_amdgcn_mfma_f32_16x16x32_f16(afr[mt], bfr, acc[mt][nt], 0, 0, 0);
            }
        }

        #pragma unroll
        for (int nt = 0; nt < 2; ++nt) {
            const int col = (nh * 8 + w * 2 + nt) * 16 + l15;
            const float bqa = bq[col];
            #pragma unroll
            for (int mt = 0; mt < 4; ++mt)
                #pragma unroll
                for (int r = 0; r < 4; ++r) {
                    const int row = l4 * 4 + r;
                    qh[(size_t)(r0 + mt * 16 + row) * EDIM + col] =
                        (HALF)fmaxf(acc[mt][nt][r] + bqa, 0.0f);
                }
        }
        return;
    }

    // ======== enc: fragment-ordered GELU(neigh@Wenc)+PE ========
    const int bidx = blockIdx.x;
    const int b = bidx >> 6;
    const int n = bidx & 63;
    const float* PE = (const float*)(ws + WS_PE);
    const int* idxT = (const int*)(ws + WS_IDX);
    HALF* encF = (HALF*)(wsout + WS_ENCF);
    HALF* enc2 = (HALF*)(wsout + WS_ENC2);

    for (int i = tid; i < HIS * 12; i += 256) {
        const int t = i / 12;
        const int d = i - t * 12;
        float val = 0.0f;
        if (d < DKA) val = kin[((b * HIS + t) * NA + idxT[n * HIS + t]) * DKA + d];
        s_neigh[t][d] = val;
    }
    __syncthreads();

    const int L  = lane & 31;
    const int th = lane >> 5;
    const int e0 = L * 8;
    float4 weA[DKA], weB[DKA];
    #pragma unroll
    for (int d = 0; d < DKA; ++d) {
        weA[d] = *reinterpret_cast<const float4*>(&Wenc[d * EDIM + e0]);
        weB[d] = *reinterpret_cast<const float4*>(&Wenc[d * EDIM + e0 + 4]);
    }

    for (int tp = w; tp < 25; tp += 4) {
        const int t = 2 * tp + th;      // 0..49
        float nv[DKA];
        #pragma unroll
        for (int d = 0; d < DKA; ++d) nv[d] = s_neigh[t][d];
        float4 xA = nv[0] * weA[0];
        float4 xB = nv[0] * weB[0];
        #pragma unroll
        for (int d = 1; d < DKA; ++d) { xA += nv[d] * weA[d]; xB += nv[d] * weB[d]; }
        const float4 peA = *reinterpret_cast<const float4*>(&PE[t * EDIM + e0]);
        const float4 peB = *reinterpret_cast<const float4*>(&PE[t * EDIM + e0 + 4]);
        float r0 = 0.5f * xA.x * (1.0f + erff(xA.x * 0.70710678118654752f)) + peA.x;
        float r1 = 0.5f * xA.y * (1.0f + erff(xA.y * 0.70710678118654752f)) + peA.y;
        float r2 = 0.5f * xA.z * (1.0f + erff(xA.z * 0.70710678118654752f)) + peA.z;
        float r3 = 0.5f * xA.w * (1.0f + erff(xA.w * 0.70710678118654752f)) + peA.w;
        float r4 = 0.5f * xB.x * (1.0f + erff(xB.x * 0.70710678118654752f)) + peB.x;
        float r5 = 0.5f * xB.y * (1.0f + erff(xB.y * 0.70710678118654752f)) + peB.y;
        float r6 = 0.5f * xB.z * (1.0f + erff(xB.z * 0.70710678118654752f)) + peB.z;
        float r7 = 0.5f * xB.w * (1.0f + erff(xB.w * 0.70710678118654752f)) + peB.w;
        half8 hv;
        hv[0] = (HALF)r0; hv[1] = (HALF)r1; hv[2] = (HALF)r2; hv[3] = (HALF)r3;
        hv[4] = (HALF)r4; hv[5] = (HALF)r5; hv[6] = (HALF)r6; hv[7] = (HALF)r7;
        if (t < 48) {
            const int kk = L >> 2;
            const int mt = t >> 4;
            const int fl = (L & 3) * 16 + (t & 15);
            const size_t off = ((((size_t)bidx * 8 + kk) * 3 + mt) * 64 + fl) * 8;
            *reinterpret_cast<half8*>(&encF[off]) = hv;
        } else {
            const size_t off = (((size_t)bidx * 2 + (t - 48)) * EDIM) + e0;
            *reinterpret_cast<half8*>(&enc2[off]) = hv;
        }
    }
}

// ---------------- K2: attention per (b,n) — LDS-staged A, single-pass dual GEMM ----------------
__global__ __launch_bounds__(256) void attn_kernel(
    const float* __restrict__ bk,
    const float* __restrict__ bv,
    const char*  __restrict__ ws,
    char* __restrict__ wsout)
{
    const int tid  = threadIdx.x;
    const int bidx = blockIdx.x;
    const int lane = tid & 63;
    const int w    = tid >> 6;
    const int l15  = lane & 15;
    const int l4   = lane >> 4;

    const HALF* WkP  = (const HALF*)(ws + WS_WKP);
    const HALF* WvP  = (const HALF*)(ws + WS_WVP);
    const HALF* qh   = (const HALF*)(ws + WS_QH);
    const HALF* encF = (const HALF*)(ws + WS_ENCF);
    const HALF* enc2 = (const HALF*)(ws + WS_ENC2);
    HALF* O = (HALF*)(wsout + WS_QH);   // overwrite own qh row at the end (safe per-row)

    __shared__ __align__(16) HALF s_A[12288];   // 24 KB: A-frags [kk][mt][lane][8], linear copy
    __shared__ __align__(16) HALF s_e2[512];    // rows t=48,49
    __shared__ float s_att[4][2][64];
    __shared__ __align__(16) float s_o[EDIM];

    // ---- one-time staged copy: this block's A-fragments -> LDS (coalesced 16B) ----
    {
        const half8* src = reinterpret_cast<const half8*>(encF + (size_t)bidx * 12288);
        half8* dst = reinterpret_cast<half8*>(s_A);
        #pragma unroll
        for (int j = 0; j < 6; ++j) dst[j * 256 + tid] = src[j * 256 + tid];
        if (tid < 64)
            reinterpret_cast<half8*>(s_e2)[tid] =
                reinterpret_cast<const half8*>(enc2 + (size_t)bidx * 512)[tid];
    }

    float qv[4], bkb[4], bvb[4];
    #pragma unroll
    for (int nt = 0; nt < 4; ++nt) {
        const int col = w * 64 + nt * 16 + l15;
        qv[nt]  = (float)qh[(size_t)bidx * EDIM + col];
        bkb[nt] = bk[col];
        bvb[nt] = bv[col];
    }

    f32x4 ka[4][4], va[4][4];
    #pragma unroll
    for (int mt = 0; mt < 4; ++mt)
        #pragma unroll
        for (int nt = 0; nt < 4; ++nt) { ka[mt][nt] = (f32x4)0.0f; va[mt][nt] = (f32x4)0.0f; }

    __syncthreads();

    #pragma unroll
    for (int kk = 0; kk < 8; ++kk) {
        half8 afr[4];
        #pragma unroll
        for (int mt = 0; mt < 3; ++mt)
            afr[mt] = *reinterpret_cast<const half8*>(&s_A[(kk * 3 + mt) * 512 + lane * 8]);
        afr[3] = *reinterpret_cast<const half8*>(&s_e2[(l15 & 1) * 256 + kk * 32 + l4 * 8]);
        if (l15 >= 2) afr[3] = (half8)(HALF)0.0f;
        #pragma unroll
        for (int nt = 0; nt < 4; ++nt) {
            const size_t boff = ((size_t)((w * 4 + nt) * 8 + kk) * 64 + lane) * 8;
            const half8 bkfr = *reinterpret_cast<const half8*>(WkP + boff);
            const half8 bvfr = *reinterpret_cast<const half8*>(WvP + boff);
            #pragma unroll
            for (int mt = 0; mt < 4; ++mt) {
                ka[mt][nt] = __builtin_amdgcn_mfma_f32_16x16x32_f16(afr[mt], bkfr, ka[mt][nt], 0, 0, 0);
                va[mt][nt] = __builtin_amdgcn_mfma_f32_16x16x32_f16(afr[mt], bvfr, va[mt][nt], 0, 0, 0);
            }
        }
    }

    // ---- logits: relu(kh+bk) · qh, 16-lane shfl reduce ----
    #pragma unroll
    for (int mt = 0; mt < 4; ++mt)
        #pragma unroll
        for (int r = 0; r < 4; ++r) {
            float p0 = qv[0] * fmaxf(ka[mt][0][r] + bkb[0], 0.0f)
                     + qv[1] * fmaxf(ka[mt][1][r] + bkb[1], 0.0f);
            float p1 = qv[2] * fmaxf(ka[mt][2][r] + bkb[2], 0.0f)
                     + qv[3] * fmaxf(ka[mt][3][r] + bkb[3], 0.0f);
            p0 += __shfl_xor(p0, 1);  p1 += __shfl_xor(p1, 1);
            p0 += __shfl_xor(p0, 2);  p1 += __shfl_xor(p1, 2);
            p0 += __shfl_xor(p0, 4);  p1 += __shfl_xor(p1, 4);
            p0 += __shfl_xor(p0, 8);  p1 += __shfl_xor(p1, 8);
            if (l15 == 0) {
                const int t = mt * 16 + l4 * 4 + r;
                s_att[w][0][t] = p0 * (1.0f / 3.0f);
                s_att[w][1][t] = p1 * (1.0f / 3.0f);
            }
        }
    __syncthreads();

    // ---- wave-parallel softmax (wave w owns its own 2 heads) ----
    {
        const int hsel = lane >> 5;
        const int tt   = lane & 31;
        const float a0  = s_att[w][hsel][tt];
        const float a1v = s_att[w][hsel][tt + 32];
        const bool  v1  = (tt + 32) < HIS;
        float m = fmaxf(a0, v1 ? a1v : -1e30f);
        m = fmaxf(m, __shfl_xor(m, 1));
        m = fmaxf(m, __shfl_xor(m, 2));
        m = fmaxf(m, __shfl_xor(m, 4));
        m = fmaxf(m, __shfl_xor(m, 8));
        m = fmaxf(m, __shfl_xor(m, 16));
        const float e0 = expf(a0 - m);
        const float e1 = v1 ? expf(a1v - m) : 0.0f;
        float s = e0 + e1;
        s += __shfl_xor(s, 1);
        s += __shfl_xor(s, 2);
        s += __shfl_xor(s, 4);
        s += __shfl_xor(s, 8);
        s += __shfl_xor(s, 16);
        const float inv = 1.0f / s;
        s_att[w][hsel][tt]      = e0 * inv;
        s_att[w][hsel][tt + 32] = e1 * inv;
    }
    __syncthreads();

    // ---- PV from va ----
    {
        float o0 = 0.f, o1 = 0.f, o2 = 0.f, o3 = 0.f;
        #pragma unroll
        for (int mt = 0; mt < 4; ++mt)
            #pragma unroll
            for (int r = 0; r < 4; ++r) {
                const int t = mt * 16 + l4 * 4 + r;
                const float a0 = s_att[w][0][t];
                const float a1 = s_att[w][1][t];
                o0 += a0 * fmaxf(va[mt][0][r] + bvb[0], 0.0f);
                o1 += a0 * fmaxf(va[mt][1][r] + bvb[1], 0.0f);
                o2 += a1 * fmaxf(va[mt][2][r] + bvb[2], 0.0f);
                o3 += a1 * fmaxf(va[mt][3][r] + bvb[3], 0.0f);
            }
        o0 += __shfl_xor(o0, 16); o1 += __shfl_xor(o1, 16);
        o2 += __shfl_xor(o2, 16); o3 += __shfl_xor(o3, 16);
        o0 += __shfl_xor(o0, 32); o1 += __shfl_xor(o1, 32);
        o2 += __shfl_xor(o2, 32); o3 += __shfl_xor(o3, 32);
        if (lane < 16) {
            s_o[w * 64 +  0 + l15] = o0;
            s_o[w * 64 + 16 + l15] = o1;
            s_o[w * 64 + 32 + l15] = o2;
            s_o[w * 64 + 48 + l15] = o3;
        }
    }
    __syncthreads();

    // ---- write O row (f16) for out_gemm ----
    O[(size_t)bidx * EDIM + tid] = (HALF)s_o[tid];
}

// ---------------- out GEMM: out = relu(O @ Wout + bout), tiles M=64 x N=128 ----------------
__global__ __launch_bounds__(256) void out_gemm(
    const float* __restrict__ bout,
    const char*  __restrict__ ws,
    float* __restrict__ out)
{
    const int tid = threadIdx.x, lane = tid & 63, w = tid >> 6;
    const int l15 = lane & 15, l4 = lane >> 4;
    const int bx  = blockIdx.x;          // 0..63
    const int r0  = (bx >> 1) * 64;
    const int nh  = bx & 1;
    const HALF* WoP = (const HALF*)(ws + WS_WOP);
    const HALF* O   = (const HALF*)(ws + WS_QH);   // attn overwrote qh rows with o

    f32x4 acc[4][2];
    #pragma unroll
    for (int mt = 0; mt < 4; ++mt)
        #pragma unroll
        for (int nt = 0; nt < 2; ++nt) acc[mt][nt] = (f32x4)0.0f;

    #pragma unroll 2
    for (int kk = 0; kk < 8; ++kk) {
        half8 afr[4];
        #pragma unroll
        for (int mt = 0; mt < 4; ++mt)
            afr[mt] = *reinterpret_cast<const half8*>(
                &O[(size_t)(r0 + mt * 16 + l15) * EDIM + kk * 32 + l4 * 8]);
        #pragma unroll
        for (int nt = 0; nt < 2; ++nt) {
            const int ntile = nh * 8 + w * 2 + nt;
            const half8 bfr = *reinterpret_cast<const half8*>(
                WoP + ((size_t)(ntile * 8 + kk) * 64 + lane) * 8);
            #pragma unroll
            for (int mt = 0; mt < 4; ++mt)
                acc[mt][nt] = __builtin_amdgcn_mfma_f32_16x16x32_f16(afr[mt], bfr, acc[mt][nt], 0, 0, 0);
        }
    }

    #pragma unroll
    for (int nt = 0; nt < 2; ++nt) {
        const int col = (nh * 8 + w * 2 + nt) * 16 + l15;
        const float boa = bout[col];
        #pragma unroll
        for (int mt = 0; mt < 4; ++mt)
            #pragma unroll
            for (int r = 0; r < 4; ++r) {
                const int row = l4 * 4 + r;
                out[(size_t)(r0 + mt * 16 + row) * EDIM + col] =
                    fmaxf(acc[mt][nt][r] + boa, 0.0f);
            }
    }
}

// ---------------- fallback (ws too small; f32 path) ----------------
__global__ __launch_bounds__(256) void mha_fallback(
    const float* __restrict__ q,
    const float* __restrict__ kin,
    const float* __restrict__ adjs,
    const float* __restrict__ Wq, const float* __restrict__ bq,
    const float* __restrict__ Wk, const float* __restrict__ bk,
    const float* __restrict__ Wv, const float* __restrict__ bv,
    const float* __restrict__ Wout, const float* __restrict__ bout,
    const float* __restrict__ Wenc,
    float* __restrict__ out)
{
    const int tid  = threadIdx.x;
    const int bidx = blockIdx.x;
    const int b = bidx >> 6;
    const int n = bidx & 63;

    __shared__ __align__(16) float s_q[EDIM];
    __shared__ __align__(16) float s_qh[EDIM];
    __shared__ __align__(16) float s_neigh[HIS][12];
    __shared__ __align__(16) float s_enc[HIS * EDIM];
    __shared__ float s_att[NV][66];
    __shared__ __align__(16) float s_opart[4][EDIM];
    __shared__ __align__(16) float s_o[EDIM];
    __shared__ int s_idx[HIS];

    s_q[tid] = q[bidx * EDIM + tid];
    if (tid < HIS) {
        const float* row = adjs + (n * HIS + tid) * NA;
        int best = 0;
        #pragma unroll
        for (int a = 0; a < NA; ++a) best = (row[a] > 0.5f) ? a : best;
        s_idx[tid] = best;
    }
    __syncthreads();

    for (int i = tid; i < HIS * 12; i += 256) {
        const int t = i / 12;
        const int d = i - t * 12;
        float val = 0.0f;
        if (d < DKA) val = kin[((b * HIS + t) * NA + s_idx[t]) * DKA + d];
        s_neigh[t][d] = val;
    }
    __syncthreads();

    {
        const int e = tid;
        float acc = bq[e];
        #pragma unroll 4
        for (int d0 = 0; d0 < EDIM; d0 += 4) {
            const float4 qv = *reinterpret_cast<const float4*>(&s_q[d0]);
            acc += qv.x * Wq[(d0 + 0) * EDIM + e];
            acc += qv.y * Wq[(d0 + 1) * EDIM + e];
            acc += qv.z * Wq[(d0 + 2) * EDIM + e];
            acc += qv.w * Wq[(d0 + 3) * EDIM + e];
        }
        s_qh[e] = fmaxf(acc, 0.0f);

        float we[12];
        #pragma unroll
        for (int j = 0; j < 12; ++j) we[j] = (j < DKA) ? Wenc[j * EDIM + e] : 0.0f;
        const float dt = expf(-(float)(e & ~1) * (9.210340371976184f / 256.0f));
        for (int t = 0; t < HIS; ++t) {
            const float4 n0 = *reinterpret_cast<const float4*>(&s_neigh[t][0]);
            const float4 n1 = *reinterpret_cast<const float4*>(&s_neigh[t][4]);
            const float4 n2 = *reinterpret_cast<const float4*>(&s_neigh[t][8]);
            float x = n0.x*we[0] + n0.y*we[1] + n0.z*we[2] + n0.w*we[3]
                    + n1.x*we[4] + n1.y*we[5] + n1.z*we[6] + n1.w*we[7]
                    + n2.x*we[8];
            x = 0.5f * x * (1.0f + erff(x * 0.70710678118654752f));
            const float arg = (float)t * dt;
            const float pe = (e & 1) ? cosf(arg) : sinf(arg);
            s_enc[t * EDIM + e] = x + pe;
        }
    }
    __syncthreads();

    const int g = tid & 63;
    const int h = tid >> 6;
    const int tbase  = (h == 0) ? 0 : (h == 1) ? 13 : (h == 2) ? 25 : 37;
    const int tcount = (h == 1 || h == 2) ? 12 : 13;
    const int v = g >> 3;

    {
        float4 kacc[13];
        const float4 bkv = *reinterpret_cast<const float4*>(&bk[4 * g]);
        #pragma unroll
        for (int tt = 0; tt < 13; ++tt) kacc[tt] = bkv;
        #pragma unroll 2
        for (int d0 = 0; d0 < EDIM; d0 += 4) {
            const float4 w0 = *reinterpret_cast<const float4*>(&Wk[(d0 + 0) * EDIM + 4 * g]);
            const float4 w1 = *reinterpret_cast<const float4*>(&Wk[(d0 + 1) * EDIM + 4 * g]);
            const float4 w2 = *reinterpret_cast<const float4*>(&Wk[(d0 + 2) * EDIM + 4 * g]);
            const float4 w3 = *reinterpret_cast<const float4*>(&Wk[(d0 + 3) * EDIM + 4 * g]);
            #pragma unroll
            for (int tt = 0; tt < 13; ++tt) {
                const float4 ev = *reinterpret_cast<const float4*>(&s_enc[(tbase + tt) * EDIM + d0]);
                kacc[tt].x += ev.x * w0.x + ev.y * w1.x + ev.z * w2.x + ev.w * w3.x;
                kacc[tt].y += ev.x * w0.y + ev.y * w1.y + ev.z * w2.y + ev.w * w3.y;
                kacc[tt].z += ev.x * w0.z + ev.y * w1.z + ev.z * w2.z + ev.w * w3.z;
                kacc[tt].w += ev.x * w0.w + ev.y * w1.w + ev.z * w2.w + ev.w * w3.w;
            }
        }
        const float4 qv = *reinterpret_cast<const float4*>(&s_qh[4 * g]);
        #pragma unroll
        for (int tt = 0; tt < 13; ++tt) {
            float p = qv.x * fmaxf(kacc[tt].x, 0.0f)
                    + qv.y * fmaxf(kacc[tt].y, 0.0f)
                    + qv.z * fmaxf(kacc[tt].z, 0.0f)
                    + qv.w * fmaxf(kacc[tt].w, 0.0f);
            p += __shfl_xor(p, 1);
            p += __shfl_xor(p, 2);
            p += __shfl_xor(p, 4);
            if ((g & 7) == 0) s_att[v][tbase + tt] = p * (1.0f / 3.0f);
        }
    }
    __syncthreads();

    if (tid < NV) {
        float m = -1e30f;
        for (int t = 0; t < HIS; ++t) m = fmaxf(m, s_att[tid][t]);
        float ssum = 0.0f;
        for (int t = 0; t < HIS; ++t) {
            const float ex = expf(s_att[tid][t] - m);
            s_att[tid][t] = ex;
            ssum += ex;
        }
        const float inv = 1.0f / ssum;
        for (int t = 0; t < HIS; ++t) s_att[tid][t] *= inv;
    }
    __syncthreads();

    {
        float4 vacc[13];
        const float4 bvv = *reinterpret_cast<const float4*>(&bv[4 * g]);
        #pragma unroll
        for (int tt = 0; tt < 13; ++tt) vacc[tt] = bvv;
        #pragma unroll 2
        for (int d0 = 0; d0 < EDIM; d0 += 4) {
            const float4 w0 = *reinterpret_cast<const float4*>(&Wv[(d0 + 0) * EDIM + 4 * g]);
            const float4 w1 = *reinterpret_cast<const float4*>(&Wv[(d0 + 1) * EDIM + 4 * g]);
            const float4 w2 = *reinterpret_cast<const float4*>(&Wv[(d0 + 2) * EDIM + 4 * g]);
            const float4 w3 = *reinterpret_cast<const float4*>(&Wv[(d0 + 3) * EDIM + 4 * g]);
            #pragma unroll
            for (int tt = 0; tt < 13; ++tt) {
                const float4 ev = *reinterpret_cast<const float4*>(&s_enc[(tbase + tt) * EDIM + d0]);
                vacc[tt].x += ev.x * w0.x + ev.y * w1.x + ev.z * w2.x + ev.w * w3.x;
                vacc[tt].y += ev.x * w0.y + ev.y * w1.y + ev.z * w2.y + ev.w * w3.y;
                vacc[tt].z += ev.x * w0.z + ev.y * w1.z + ev.z * w2.z + ev.w * w3.z;
                vacc[tt].w += ev.x * w0.w + ev.y * w1.w + ev.z * w2.w + ev.w * w3.w;
            }
        }
        float4 po = make_float4(0.0f, 0.0f, 0.0f, 0.0f);
        #pragma unroll
        for (int tt = 0; tt < 13; ++tt) {
            if (tt < tcount) {
                const float a = s_att[v][tbase + tt];
                po.x += a * fmaxf(vacc[tt].x, 0.0f);
                po.y += a * fmaxf(vacc[tt].y, 0.0f);
                po.z += a * fmaxf(vacc[tt].z, 0.0f);
                po.w += a * fmaxf(vacc[tt].w, 0.0f);
            }
        }
        *reinterpret_cast<float4*>(&s_opart[h][4 * g]) = po;
    }
    __syncthreads();

    s_o[tid] = s_opart[0][tid] + s_opart[1][tid] + s_opart[2][tid] + s_opart[3][tid];
    __syncthreads();

    {
        const int e = tid;
        float acc = bout[e];
        #pragma unroll 4
        for (int d0 = 0; d0 < EDIM; d0 += 4) {
            const float4 ov = *reinterpret_cast<const float4*>(&s_o[d0]);
            acc += ov.x * Wout[(d0 + 0) * EDIM + e];
            acc += ov.y * Wout[(d0 + 1) * EDIM + e];
            acc += ov.z * Wout[(d0 + 2) * EDIM + e];
            acc += ov.w * Wout[(d0 + 3) * EDIM + e];
        }
        out[bidx * EDIM + e] = fmaxf(acc, 0.0f);
    }
}

extern "C" void kernel_launch(void* const* d_in, const int* in_sizes, int n_in,
                              void* d_out, int out_size, void* d_ws, size_t ws_size,
                              hipStream_t stream) {
    const float* q    = (const float*)d_in[0];
    const float* kin  = (const float*)d_in[1];
    const float* adjs = (const float*)d_in[2];
    const float* Wq   = (const float*)d_in[3];
    const float* bq   = (const float*)d_in[4];
    const float* Wk   = (const float*)d_in[5];
    const float* bk   = (const float*)d_in[6];
    const float* Wv   = (const float*)d_in[7];
    const float* bv   = (const float*)d_in[8];
    const float* Wout = (const float*)d_in[9];
    const float* bout = (const float*)d_in[10];
    const float* Wenc = (const float*)d_in[11];
    float* out = (float*)d_out;
    char* ws = (char*)d_ws;

    if (ws_size >= WS_NEED) {
        hipLaunchKernelGGL(pack_setup, dim3(256), dim3(256), 0, stream,
                           Wk, Wv, Wq, Wout, adjs, ws);
        hipLaunchKernelGGL(enc_qh, dim3(NB * NA + 64), dim3(256), 0, stream,
                           q, kin, bq, Wenc, ws, ws);
        hipLaunchKernelGGL(attn_kernel, dim3(NB * NA), dim3(256), 0, stream,
                           bk, bv, ws, ws);
        hipLaunchKernelGGL(out_gemm, dim3(64), dim3(256), 0, stream,
                           bout, ws, out);
    } else {
        hipLaunchKernelGGL(mha_fallback, dim3(NB * NA), dim3(256), 0, stream,
                           q, kin, adjs, Wq, bq, Wk, bk, Wv, bv, Wout, bout, Wenc, out);
    }
}

// Round 8
// 104.592 us; speedup vs baseline: 1.2276x; 1.0465x over previous
//
#include <hip/hip_runtime.h>
#include <math.h>

#define NB   32
#define NA   64
#define EDIM 256
#define HIS  50
#define DKA  9
#define NV   8

typedef _Float16 HALF;
typedef _Float16 half8 __attribute__((ext_vector_type(8)));
typedef float    f32x4 __attribute__((ext_vector_type(4)));

// ws layout (bytes):
#define WS_WKP   0          // f16 B-frag-packed Wk                  131072
#define WS_WVP   131072     // f16 B-frag-packed Wv                  131072
#define WS_WQP   262144     // f16 B-frag-packed Wq                  131072
#define WS_WOP   393216     // f16 B-frag-packed Wout                131072
#define WS_PE    524288     // f32 PE [50][256]                      51200
#define WS_IDX   575488     // int idxTab [64][50]                   12800
#define WS_QH    588288     // f16 [2048][256]: qh, then overwritten by O (per-row, safe)
#define WS_NEED  1636864ULL

// ---------------- setup: pack weights (B-fragment order), PE, adjacency ----------------
__global__ __launch_bounds__(256) void pack_setup(
    const float* __restrict__ Wk, const float* __restrict__ Wv,
    const float* __restrict__ Wq, const float* __restrict__ Wout,
    const float* __restrict__ adjs,
    char* __restrict__ ws)
{
    const int tid = blockIdx.x * 256 + threadIdx.x;   // 0..65535
    HALF* WkP  = (HALF*)(ws + WS_WKP);
    HALF* WvP  = (HALF*)(ws + WS_WVP);
    HALF* WqP  = (HALF*)(ws + WS_WQP);
    HALF* WoP  = (HALF*)(ws + WS_WOP);
    float* PE  = (float*)(ws + WS_PE);
    int*  idxT = (int*)(ws + WS_IDX);

    // B-fragment pack: out = ((ntile*8 + ktile)*64 + lane)*8 + elem
    {
        const int elem = tid & 7;
        const int lane = (tid >> 3) & 63;
        const int kt   = (tid >> 9) & 7;
        const int nt   = tid >> 12;
        const int k = kt * 32 + (lane >> 4) * 8 + elem;
        const int n = nt * 16 + (lane & 15);
        WkP[tid] = (HALF)Wk[k * EDIM + n];
        WvP[tid] = (HALF)Wv[k * EDIM + n];
        WqP[tid] = (HALF)Wq[k * EDIM + n];
        WoP[tid] = (HALF)Wout[k * EDIM + n];
    }
    // positional encoding table
    if (tid < HIS * EDIM) {
        const int t = tid >> 8;
        const int e = tid & 255;
        const float dt = expf(-(float)(e & ~1) * (9.210340371976184f / 256.0f));
        const float arg = (float)t * dt;
        PE[tid] = (e & 1) ? cosf(arg) : sinf(arg);
    }
    // adjacency one-hot -> index
    if (tid < NA * HIS) {
        const float* row = adjs + tid * NA;   // tid = n*HIS + t
        int best = 0;
        #pragma unroll
        for (int a = 0; a < NA; ++a) best = (row[a] > 0.5f) ? a : best;
        idxT[tid] = best;
    }
}

// ---------------- qh GEMM: qh = relu(q @ Wq + bq), f16 out. Tiles M=64 x N=128 ----------------
__global__ __launch_bounds__(256) void qh_gemm(
    const float* __restrict__ q,
    const float* __restrict__ bq,
    const char*  __restrict__ ws,
    char* __restrict__ wsout)
{
    const int tid = threadIdx.x, lane = tid & 63, w = tid >> 6;
    const int l15 = lane & 15, l4 = lane >> 4;
    const int bx  = blockIdx.x;              // 0..63
    const int r0  = (bx >> 1) * 64;
    const int nh  = bx & 1;
    const HALF* WqP = (const HALF*)(ws + WS_WQP);
    HALF* qh = (HALF*)(wsout + WS_QH);

    f32x4 acc[4][2];
    #pragma unroll
    for (int mt = 0; mt < 4; ++mt)
        #pragma unroll
        for (int nt = 0; nt < 2; ++nt) acc[mt][nt] = (f32x4)0.0f;

    #pragma unroll 2
    for (int kk = 0; kk < 8; ++kk) {
        half8 afr[4];
        #pragma unroll
        for (int mt = 0; mt < 4; ++mt) {
            const float* ap = &q[(size_t)(r0 + mt * 16 + l15) * EDIM + kk * 32 + l4 * 8];
            const float4 a0 = *reinterpret_cast<const float4*>(ap);
            const float4 a1 = *reinterpret_cast<const float4*>(ap + 4);
            half8 h;
            h[0] = (HALF)a0.x; h[1] = (HALF)a0.y; h[2] = (HALF)a0.z; h[3] = (HALF)a0.w;
            h[4] = (HALF)a1.x; h[5] = (HALF)a1.y; h[6] = (HALF)a1.z; h[7] = (HALF)a1.w;
            afr[mt] = h;
        }
        #pragma unroll
        for (int nt = 0; nt < 2; ++nt) {
            const int ntile = nh * 8 + w * 2 + nt;
            const half8 bfr = *reinterpret_cast<const half8*>(
                WqP + ((size_t)(ntile * 8 + kk) * 64 + lane) * 8);
            #pragma unroll
            for (int mt = 0; mt < 4; ++mt)
                acc[mt][nt] = __builtin_amdgcn_mfma_f32_16x16x32_f16(afr[mt], bfr, acc[mt][nt], 0, 0, 0);
        }
    }

    #pragma unroll
    for (int nt = 0; nt < 2; ++nt) {
        const int col = (nh * 8 + w * 2 + nt) * 16 + l15;
        const float bqa = bq[col];
        #pragma unroll
        for (int mt = 0; mt < 4; ++mt)
            #pragma unroll
            for (int r = 0; r < 4; ++r) {
                const int row = l4 * 4 + r;
                qh[(size_t)(r0 + mt * 16 + row) * EDIM + col] =
                    (HALF)fmaxf(acc[mt][nt][r] + bqa, 0.0f);
            }
    }
}

// ---------------- fused enc+attention: 2 (b,n) per block, 8 waves (1 head/wave) ----------------
__global__ __launch_bounds__(512) void attn_fused(
    const float* __restrict__ kin,
    const float* __restrict__ bk,
    const float* __restrict__ bv,
    const float* __restrict__ Wenc,
    const char*  __restrict__ ws,
    char* __restrict__ wsout)
{
    const int tid  = threadIdx.x;
    const int lane = tid & 63;
    const int w    = tid >> 6;          // wave 0..7 -> head w
    const int l15  = lane & 15;
    const int l4   = lane >> 4;
    const int bidx0 = blockIdx.x * 2;

    const HALF* WkP  = (const HALF*)(ws + WS_WKP);
    const HALF* WvP  = (const HALF*)(ws + WS_WVP);
    const HALF* qh   = (const HALF*)(ws + WS_QH);
    const float* PE  = (const float*)(ws + WS_PE);
    const int*  idxT = (const int*)(ws + WS_IDX);
    HALF* O = (HALF*)(wsout + WS_QH);   // overwrite own 2 qh rows at the end

    __shared__ __align__(16) HALF  s_A[2 * 8 * 4 * 64 * 8];  // 64 KB A-frags [g][kk][mt][fl][8]
    __shared__ __align__(16) float s_neigh[2][HIS][12];
    __shared__ float s_att[NV][2][64];                       // [wave][g][t] (wave-private)
    __shared__ __align__(16) float s_o[2][EDIM];

    // ---- gather neighbor actions for both bidx ----
    for (int i = tid; i < 2 * HIS * 12; i += 512) {
        const int g   = i / (HIS * 12);
        const int rem = i - g * (HIS * 12);
        const int t = rem / 12;
        const int d = rem - t * 12;
        const int bidx = bidx0 + g;
        const int b = bidx >> 6, n = bidx & 63;
        float val = 0.0f;
        if (d < DKA) val = kin[((b * HIS + t) * NA + idxT[n * HIS + t]) * DKA + d];
        s_neigh[g][t][d] = val;
    }
    __syncthreads();

    // ---- enc phase: GELU(neigh@Wenc)+PE -> s_A in fragment layout ----
    {
        const int eg   = tid & 31;        // e-group: e0 = 8*eg
        const int slot = (tid >> 5) & 7;  // t slot (stride 8)
        const int g    = tid >> 8;        // which bidx
        const int e0   = eg * 8;
        float4 weA[DKA], weB[DKA];
        #pragma unroll
        for (int d = 0; d < DKA; ++d) {
            weA[d] = *reinterpret_cast<const float4*>(&Wenc[d * EDIM + e0]);
            weB[d] = *reinterpret_cast<const float4*>(&Wenc[d * EDIM + e0 + 4]);
        }
        for (int t = slot; t < HIS; t += 8) {
            float nv[DKA];
            #pragma unroll
            for (int d = 0; d < DKA; ++d) nv[d] = s_neigh[g][t][d];
            float4 xA = nv[0] * weA[0];
            float4 xB = nv[0] * weB[0];
            #pragma unroll
            for (int d = 1; d < DKA; ++d) { xA += nv[d] * weA[d]; xB += nv[d] * weB[d]; }
            const float4 peA = *reinterpret_cast<const float4*>(&PE[t * EDIM + e0]);
            const float4 peB = *reinterpret_cast<const float4*>(&PE[t * EDIM + e0 + 4]);
            float r0 = 0.5f * xA.x * (1.0f + erff(xA.x * 0.70710678118654752f)) + peA.x;
            float r1 = 0.5f * xA.y * (1.0f + erff(xA.y * 0.70710678118654752f)) + peA.y;
            float r2 = 0.5f * xA.z * (1.0f + erff(xA.z * 0.70710678118654752f)) + peA.z;
            float r3 = 0.5f * xA.w * (1.0f + erff(xA.w * 0.70710678118654752f)) + peA.w;
            float r4 = 0.5f * xB.x * (1.0f + erff(xB.x * 0.70710678118654752f)) + peB.x;
            float r5 = 0.5f * xB.y * (1.0f + erff(xB.y * 0.70710678118654752f)) + peB.y;
            float r6 = 0.5f * xB.z * (1.0f + erff(xB.z * 0.70710678118654752f)) + peB.z;
            float r7 = 0.5f * xB.w * (1.0f + erff(xB.w * 0.70710678118654752f)) + peB.w;
            half8 hv;
            hv[0] = (HALF)r0; hv[1] = (HALF)r1; hv[2] = (HALF)r2; hv[3] = (HALF)r3;
            hv[4] = (HALF)r4; hv[5] = (HALF)r5; hv[6] = (HALF)r6; hv[7] = (HALF)r7;
            const int kk = eg >> 2;
            const int mt = t >> 4;
            const int fl = (eg & 3) * 16 + (t & 15);
            *reinterpret_cast<half8*>(&s_A[(((g * 8 + kk) * 4 + mt) * 64 + fl) * 8]) = hv;
        }
        // zero pad rows t = 50..63 (mt=3 tile)
        const half8 z = (half8)(HALF)0.0f;
        for (int i = tid; i < 2 * 14 * 32; i += 512) {
            const int g2  = i / 448;
            const int rem = i - g2 * 448;
            const int t   = 50 + (rem >> 5);
            const int eg2 = rem & 31;
            const int kk = eg2 >> 2;
            const int fl = (eg2 & 3) * 16 + (t & 15);
            *reinterpret_cast<half8*>(&s_A[(((g2 * 8 + kk) * 4 + 3) * 64 + fl) * 8]) = z;
        }
    }

    // ---- per-wave constants: qh, biases for head w (cols w*32 .. w*32+31) ----
    float qv[2][2], bkb[2], bvb[2];
    #pragma unroll
    for (int nt = 0; nt < 2; ++nt) {
        const int col = w * 32 + nt * 16 + l15;
        bkb[nt] = bk[col];
        bvb[nt] = bv[col];
        qv[0][nt] = (float)qh[(size_t)(bidx0 + 0) * EDIM + col];
        qv[1][nt] = (float)qh[(size_t)(bidx0 + 1) * EDIM + col];
    }

    f32x4 ka[2][4][2], va[2][4][2];
    #pragma unroll
    for (int g = 0; g < 2; ++g)
        #pragma unroll
        for (int mt = 0; mt < 4; ++mt)
            #pragma unroll
            for (int nt = 0; nt < 2; ++nt) { ka[g][mt][nt] = (f32x4)0.0f; va[g][mt][nt] = (f32x4)0.0f; }

    __syncthreads();

    // ---- K-loop: dual GEMM (kh & vh), both bidx, head w (ntile = w*2+nt covers all 16) ----
    #pragma unroll
    for (int kk = 0; kk < 8; ++kk) {
        half8 afr[2][4];
        #pragma unroll
        for (int g = 0; g < 2; ++g)
            #pragma unroll
            for (int mt = 0; mt < 4; ++mt)
                afr[g][mt] = *reinterpret_cast<const half8*>(
                    &s_A[(((g * 8 + kk) * 4 + mt) * 64 + lane) * 8]);
        #pragma unroll
        for (int nt = 0; nt < 2; ++nt) {
            const size_t boff = ((size_t)((w * 2 + nt) * 8 + kk) * 64 + lane) * 8;
            const half8 bkfr = *reinterpret_cast<const half8*>(WkP + boff);
            const half8 bvfr = *reinterpret_cast<const half8*>(WvP + boff);
            #pragma unroll
            for (int g = 0; g < 2; ++g)
                #pragma unroll
                for (int mt = 0; mt < 4; ++mt) {
                    ka[g][mt][nt] = __builtin_amdgcn_mfma_f32_16x16x32_f16(afr[g][mt], bkfr, ka[g][mt][nt], 0, 0, 0);
                    va[g][mt][nt] = __builtin_amdgcn_mfma_f32_16x16x32_f16(afr[g][mt], bvfr, va[g][mt][nt], 0, 0, 0);
                }
        }
    }

    // ---- logits: relu(kh+bk) . qh over the 32 head dims (16-lane reduce) ----
    #pragma unroll
    for (int g = 0; g < 2; ++g)
        #pragma unroll
        for (int mt = 0; mt < 4; ++mt)
            #pragma unroll
            for (int r = 0; r < 4; ++r) {
                float p = qv[g][0] * fmaxf(ka[g][mt][0][r] + bkb[0], 0.0f)
                        + qv[g][1] * fmaxf(ka[g][mt][1][r] + bkb[1], 0.0f);
                p += __shfl_xor(p, 1);
                p += __shfl_xor(p, 2);
                p += __shfl_xor(p, 4);
                p += __shfl_xor(p, 8);
                if (l15 == 0) s_att[w][g][mt * 16 + l4 * 4 + r] = p * (1.0f / 3.0f);
            }

    // ---- wave-parallel softmax: lane-half handles one bidx (wave-private s_att) ----
    {
        const int g  = lane >> 5;
        const int tt = lane & 31;
        const float a0  = s_att[w][g][tt];
        const float a1v = s_att[w][g][tt + 32];
        const bool  v1  = (tt + 32) < HIS;
        float m = fmaxf(a0, v1 ? a1v : -1e30f);
        m = fmaxf(m, __shfl_xor(m, 1));
        m = fmaxf(m, __shfl_xor(m, 2));
        m = fmaxf(m, __shfl_xor(m, 4));
        m = fmaxf(m, __shfl_xor(m, 8));
        m = fmaxf(m, __shfl_xor(m, 16));
        const float e0 = expf(a0 - m);
        const float e1 = v1 ? expf(a1v - m) : 0.0f;
        float s = e0 + e1;
        s += __shfl_xor(s, 1);
        s += __shfl_xor(s, 2);
        s += __shfl_xor(s, 4);
        s += __shfl_xor(s, 8);
        s += __shfl_xor(s, 16);
        const float inv = 1.0f / s;
        s_att[w][g][tt]      = e0 * inv;
        s_att[w][g][tt + 32] = e1 * inv;
    }

    // ---- PV ----
    {
        float o00 = 0.f, o01 = 0.f, o10 = 0.f, o11 = 0.f;
        #pragma unroll
        for (int mt = 0; mt < 4; ++mt)
            #pragma unroll
            for (int r = 0; r < 4; ++r) {
                const int t = mt * 16 + l4 * 4 + r;
                const float a0 = s_att[w][0][t];
                const float a1 = s_att[w][1][t];
                o00 += a0 * fmaxf(va[0][mt][0][r] + bvb[0], 0.0f);
                o01 += a0 * fmaxf(va[0][mt][1][r] + bvb[1], 0.0f);
                o10 += a1 * fmaxf(va[1][mt][0][r] + bvb[0], 0.0f);
                o11 += a1 * fmaxf(va[1][mt][1][r] + bvb[1], 0.0f);
            }
        o00 += __shfl_xor(o00, 16); o01 += __shfl_xor(o01, 16);
        o10 += __shfl_xor(o10, 16); o11 += __shfl_xor(o11, 16);
        o00 += __shfl_xor(o00, 32); o01 += __shfl_xor(o01, 32);
        o10 += __shfl_xor(o10, 32); o11 += __shfl_xor(o11, 32);
        if (lane < 16) {
            s_o[0][w * 32 +  0 + l15] = o00;
            s_o[0][w * 32 + 16 + l15] = o01;
            s_o[1][w * 32 +  0 + l15] = o10;
            s_o[1][w * 32 + 16 + l15] = o11;
        }
    }
    __syncthreads();

    // ---- write O rows (f16) for out_gemm ----
    {
        const int g = tid >> 8;
        const int c = tid & 255;
        O[(size_t)(bidx0 + g) * EDIM + c] = (HALF)s_o[g][c];
    }
}

// ---------------- out GEMM: out = relu(O @ Wout + bout), tiles M=64 x N=128 ----------------
__global__ __launch_bounds__(256) void out_gemm(
    const float* __restrict__ bout,
    const char*  __restrict__ ws,
    float* __restrict__ out)
{
    const int tid = threadIdx.x, lane = tid & 63, w = tid >> 6;
    const int l15 = lane & 15, l4 = lane >> 4;
    const int bx  = blockIdx.x;          // 0..63
    const int r0  = (bx >> 1) * 64;
    const int nh  = bx & 1;
    const HALF* WoP = (const HALF*)(ws + WS_WOP);
    const HALF* O   = (const HALF*)(ws + WS_QH);

    f32x4 acc[4][2];
    #pragma unroll
    for (int mt = 0; mt < 4; ++mt)
        #pragma unroll
        for (int nt = 0; nt < 2; ++nt) acc[mt][nt] = (f32x4)0.0f;

    #pragma unroll 2
    for (int kk = 0; kk < 8; ++kk) {
        half8 afr[4];
        #pragma unroll
        for (int mt = 0; mt < 4; ++mt)
            afr[mt] = *reinterpret_cast<const half8*>(
                &O[(size_t)(r0 + mt * 16 + l15) * EDIM + kk * 32 + l4 * 8]);
        #pragma unroll
        for (int nt = 0; nt < 2; ++nt) {
            const int ntile = nh * 8 + w * 2 + nt;
            const half8 bfr = *reinterpret_cast<const half8*>(
                WoP + ((size_t)(ntile * 8 + kk) * 64 + lane) * 8);
            #pragma unroll
            for (int mt = 0; mt < 4; ++mt)
                acc[mt][nt] = __builtin_amdgcn_mfma_f32_16x16x32_f16(afr[mt], bfr, acc[mt][nt], 0, 0, 0);
        }
    }

    #pragma unroll
    for (int nt = 0; nt < 2; ++nt) {
        const int col = (nh * 8 + w * 2 + nt) * 16 + l15;
        const float boa = bout[col];
        #pragma unroll
        for (int mt = 0; mt < 4; ++mt)
            #pragma unroll
            for (int r = 0; r < 4; ++r) {
                const int row = l4 * 4 + r;
                out[(size_t)(r0 + mt * 16 + row) * EDIM + col] =
                    fmaxf(acc[mt][nt][r] + boa, 0.0f);
            }
    }
}

// ---------------- fallback (ws too small; f32 path) ----------------
__global__ __launch_bounds__(256) void mha_fallback(
    const float* __restrict__ q,
    const float* __restrict__ kin,
    const float* __restrict__ adjs,
    const float* __restrict__ Wq, const float* __restrict__ bq,
    const float* __restrict__ Wk, const float* __restrict__ bk,
    const float* __restrict__ Wv, const float* __restrict__ bv,
    const float* __restrict__ Wout, const float* __restrict__ bout,
    const float* __restrict__ Wenc,
    float* __restrict__ out)
{
    const int tid  = threadIdx.x;
    const int bidx = blockIdx.x;
    const int b = bidx >> 6;
    const int n = bidx & 63;

    __shared__ __align__(16) float s_q[EDIM];
    __shared__ __align__(16) float s_qh[EDIM];
    __shared__ __align__(16) float s_neigh[HIS][12];
    __shared__ __align__(16) float s_enc[HIS * EDIM];
    __shared__ float s_att[NV][66];
    __shared__ __align__(16) float s_opart[4][EDIM];
    __shared__ __align__(16) float s_o[EDIM];
    __shared__ int s_idx[HIS];

    s_q[tid] = q[bidx * EDIM + tid];
    if (tid < HIS) {
        const float* row = adjs + (n * HIS + tid) * NA;
        int best = 0;
        #pragma unroll
        for (int a = 0; a < NA; ++a) best = (row[a] > 0.5f) ? a : best;
        s_idx[tid] = best;
    }
    __syncthreads();

    for (int i = tid; i < HIS * 12; i += 256) {
        const int t = i / 12;
        const int d = i - t * 12;
        float val = 0.0f;
        if (d < DKA) val = kin[((b * HIS + t) * NA + s_idx[t]) * DKA + d];
        s_neigh[t][d] = val;
    }
    __syncthreads();

    {
        const int e = tid;
        float acc = bq[e];
        #pragma unroll 4
        for (int d0 = 0; d0 < EDIM; d0 += 4) {
            const float4 qv = *reinterpret_cast<const float4*>(&s_q[d0]);
            acc += qv.x * Wq[(d0 + 0) * EDIM + e];
            acc += qv.y * Wq[(d0 + 1) * EDIM + e];
            acc += qv.z * Wq[(d0 + 2) * EDIM + e];
            acc += qv.w * Wq[(d0 + 3) * EDIM + e];
        }
        s_qh[e] = fmaxf(acc, 0.0f);

        float we[12];
        #pragma unroll
        for (int j = 0; j < 12; ++j) we[j] = (j < DKA) ? Wenc[j * EDIM + e] : 0.0f;
        const float dt = expf(-(float)(e & ~1) * (9.210340371976184f / 256.0f));
        for (int t = 0; t < HIS; ++t) {
            const float4 n0 = *reinterpret_cast<const float4*>(&s_neigh[t][0]);
            const float4 n1 = *reinterpret_cast<const float4*>(&s_neigh[t][4]);
            const float4 n2 = *reinterpret_cast<const float4*>(&s_neigh[t][8]);
            float x = n0.x*we[0] + n0.y*we[1] + n0.z*we[2] + n0.w*we[3]
                    + n1.x*we[4] + n1.y*we[5] + n1.z*we[6] + n1.w*we[7]
                    + n2.x*we[8];
            x = 0.5f * x * (1.0f + erff(x * 0.70710678118654752f));
            const float arg = (float)t * dt;
            const float pe = (e & 1) ? cosf(arg) : sinf(arg);
            s_enc[t * EDIM + e] = x + pe;
        }
    }
    __syncthreads();

    const int g = tid & 63;
    const int h = tid >> 6;
    const int tbase  = (h == 0) ? 0 : (h == 1) ? 13 : (h == 2) ? 25 : 37;
    const int tcount = (h == 1 || h == 2) ? 12 : 13;
    const int v = g >> 3;

    {
        float4 kacc[13];
        const float4 bkv = *reinterpret_cast<const float4*>(&bk[4 * g]);
        #pragma unroll
        for (int tt = 0; tt < 13; ++tt) kacc[tt] = bkv;
        #pragma unroll 2
        for (int d0 = 0; d0 < EDIM; d0 += 4) {
            const float4 w0 = *reinterpret_cast<const float4*>(&Wk[(d0 + 0) * EDIM + 4 * g]);
            const float4 w1 = *reinterpret_cast<const float4*>(&Wk[(d0 + 1) * EDIM + 4 * g]);
            const float4 w2 = *reinterpret_cast<const float4*>(&Wk[(d0 + 2) * EDIM + 4 * g]);
            const float4 w3 = *reinterpret_cast<const float4*>(&Wk[(d0 + 3) * EDIM + 4 * g]);
            #pragma unroll
            for (int tt = 0; tt < 13; ++tt) {
                const float4 ev = *reinterpret_cast<const float4*>(&s_enc[(tbase + tt) * EDIM + d0]);
                kacc[tt].x += ev.x * w0.x + ev.y * w1.x + ev.z * w2.x + ev.w * w3.x;
                kacc[tt].y += ev.x * w0.y + ev.y * w1.y + ev.z * w2.y + ev.w * w3.y;
                kacc[tt].z += ev.x * w0.z + ev.y * w1.z + ev.z * w2.z + ev.w * w3.z;
                kacc[tt].w += ev.x * w0.w + ev.y * w1.w + ev.z * w2.w + ev.w * w3.w;
            }
        }
        const float4 qv = *reinterpret_cast<const float4*>(&s_qh[4 * g]);
        #pragma unroll
        for (int tt = 0; tt < 13; ++tt) {
            float p = qv.x * fmaxf(kacc[tt].x, 0.0f)
                    + qv.y * fmaxf(kacc[tt].y, 0.0f)
                    + qv.z * fmaxf(kacc[tt].z, 0.0f)
                    + qv.w * fmaxf(kacc[tt].w, 0.0f);
            p += __shfl_xor(p, 1);
            p += __shfl_xor(p, 2);
            p += __shfl_xor(p, 4);
            if ((g & 7) == 0) s_att[v][tbase + tt] = p * (1.0f / 3.0f);
        }
    }
    __syncthreads();

    if (tid < NV) {
        float m = -1e30f;
        for (int t = 0; t < HIS; ++t) m = fmaxf(m, s_att[tid][t]);
        float ssum = 0.0f;
        for (int t = 0; t < HIS; ++t) {
            const float ex = expf(s_att[tid][t] - m);
            s_att[tid][t] = ex;
            ssum += ex;
        }
        const float inv = 1.0f / ssum;
        for (int t = 0; t < HIS; ++t) s_att[tid][t] *= inv;
    }
    __syncthreads();

    {
        float4 vacc[13];
        const float4 bvv = *reinterpret_cast<const float4*>(&bv[4 * g]);
        #pragma unroll
        for (int tt = 0; tt < 13; ++tt) vacc[tt] = bvv;
        #pragma unroll 2
        for (int d0 = 0; d0 < EDIM; d0 += 4) {
            const float4 w0 = *reinterpret_cast<const float4*>(&Wv[(d0 + 0) * EDIM + 4 * g]);
            const float4 w1 = *reinterpret_cast<const float4*>(&Wv[(d0 + 1) * EDIM + 4 * g]);
            const float4 w2 = *reinterpret_cast<const float4*>(&Wv[(d0 + 2) * EDIM + 4 * g]);
            const float4 w3 = *reinterpret_cast<const float4*>(&Wv[(d0 + 3) * EDIM + 4 * g]);
            #pragma unroll
            for (int tt = 0; tt < 13; ++tt) {
                const float4 ev = *reinterpret_cast<const float4*>(&s_enc[(tbase + tt) * EDIM + d0]);
                vacc[tt].x += ev.x * w0.x + ev.y * w1.x + ev.z * w2.x + ev.w * w3.x;
                vacc[tt].y += ev.x * w0.y + ev.y * w1.y + ev.z * w2.y + ev.w * w3.y;
                vacc[tt].z += ev.x * w0.z + ev.y * w1.z + ev.z * w2.z + ev.w * w3.z;
                vacc[tt].w += ev.x * w0.w + ev.y * w1.w + ev.z * w2.w + ev.w * w3.w;
            }
        }
        float4 po = make_float4(0.0f, 0.0f, 0.0f, 0.0f);
        #pragma unroll
        for (int tt = 0; tt < 13; ++tt) {
            if (tt < tcount) {
                const float a = s_att[v][tbase + tt];
                po.x += a * fmaxf(vacc[tt].x, 0.0f);
                po.y += a * fmaxf(vacc[tt].y, 0.0f);
                po.z += a * fmaxf(vacc[tt].z, 0.0f);
                po.w += a * fmaxf(vacc[tt].w, 0.0f);
            }
        }
        *reinterpret_cast<float4*>(&s_opart[h][4 * g]) = po;
    }
    __syncthreads();

    s_o[tid] = s_opart[0][tid] + s_opart[1][tid] + s_opart[2][tid] + s_opart[3][tid];
    __syncthreads();

    {
        const int e = tid;
        float acc = bout[e];
        #pragma unroll 4
        for (int d0 = 0; d0 < EDIM; d0 += 4) {
            const float4 ov = *reinterpret_cast<const float4*>(&s_o[d0]);
            acc += ov.x * Wout[(d0 + 0) * EDIM + e];
            acc += ov.y * Wout[(d0 + 1) * EDIM + e];
            acc += ov.z * Wout[(d0 + 2) * EDIM + e];
            acc += ov.w * Wout[(d0 + 3) * EDIM + e];
        }
        out[bidx * EDIM + e] = fmaxf(acc, 0.0f);
    }
}

extern "C" void kernel_launch(void* const* d_in, const int* in_sizes, int n_in,
                              void* d_out, int out_size, void* d_ws, size_t ws_size,
                              hipStream_t stream) {
    const float* q    = (const float*)d_in[0];
    const float* kin  = (const float*)d_in[1];
    const float* adjs = (const float*)d_in[2];
    const float* Wq   = (const float*)d_in[3];
    const float* bq   = (const float*)d_in[4];
    const float* Wk   = (const float*)d_in[5];
    const float* bk   = (const float*)d_in[6];
    const float* Wv   = (const float*)d_in[7];
    const float* bv   = (const float*)d_in[8];
    const float* Wout = (const float*)d_in[9];
    const float* bout = (const float*)d_in[10];
    const float* Wenc = (const float*)d_in[11];
    float* out = (float*)d_out;
    char* ws = (char*)d_ws;

    if (ws_size >= WS_NEED) {
        hipLaunchKernelGGL(pack_setup, dim3(256), dim3(256), 0, stream,
                           Wk, Wv, Wq, Wout, adjs, ws);
        hipLaunchKernelGGL(qh_gemm, dim3(64), dim3(256), 0, stream,
                           q, bq, ws, ws);
        hipLaunchKernelGGL(attn_fused, dim3(NB * NA / 2), dim3(512), 0, stream,
                           kin, bk, bv, Wenc, ws, ws);
        hipLaunchKernelGGL(out_gemm, dim3(64), dim3(256), 0, stream,
                           bout, ws, out);
    } else {
        hipLaunchKernelGGL(mha_fallback, dim3(NB * NA), dim3(256), 0, stream,
                           q, kin, adjs, Wq, bq, Wk, bk, Wv, bv, Wout, bout, Wenc, out);
    }
}

// Round 9
// 83.263 us; speedup vs baseline: 1.5421x; 1.2562x over previous
//
#include <hip/hip_runtime.h>
#include <math.h>

#define NB   32
#define NA   64
#define EDIM 256
#define HIS  50
#define DKA  9
#define NV   8

typedef _Float16 HALF;
typedef _Float16 half4 __attribute__((ext_vector_type(4)));
typedef _Float16 half8 __attribute__((ext_vector_type(8)));
typedef float    f32x4 __attribute__((ext_vector_type(4)));

// ws layout (bytes):
#define WS_WKP   0          // f16 B-frag-packed Wk                  131072
#define WS_WVP   131072     // f16 B-frag-packed Wv                  131072
#define WS_WQP   262144     // f16 B-frag-packed Wq                  131072
#define WS_WOP   393216     // f16 B-frag-packed Wout                131072
#define WS_PE    524288     // f32 PE [50][256]                      51200
#define WS_IDX   575488     // int idxTab [64][50]                   12800
#define WS_QH    588288     // f16 [2048][256]: qh, then overwritten by O (per-row, safe)
#define WS_NEED  1636864ULL

// Branchless exact-GELU: erf via Abramowitz-Stegun 7.1.26 (|err| <= 1.5e-7)
__device__ __forceinline__ float gelu_exact(float x) {
    const float ax = fabsf(x) * 0.70710678118654752f;
    const float t  = __builtin_amdgcn_rcpf(1.0f + 0.3275911f * ax);
    const float p  = t * (0.254829592f + t * (-0.284496736f + t * (1.421413741f
                   + t * (-1.453152027f + t * 1.061405429f))));
    const float er = 1.0f - p * __expf(-ax * ax);
    return 0.5f * x * (1.0f + copysignf(er, x));
}

// ---------------- setup: pack weights (B-fragment order), PE, adjacency ----------------
__global__ __launch_bounds__(256) void pack_setup(
    const float* __restrict__ Wk, const float* __restrict__ Wv,
    const float* __restrict__ Wq, const float* __restrict__ Wout,
    const float* __restrict__ adjs,
    char* __restrict__ ws)
{
    const int tid = blockIdx.x * 256 + threadIdx.x;   // 0..65535
    HALF* WkP  = (HALF*)(ws + WS_WKP);
    HALF* WvP  = (HALF*)(ws + WS_WVP);
    HALF* WqP  = (HALF*)(ws + WS_WQP);
    HALF* WoP  = (HALF*)(ws + WS_WOP);
    float* PE  = (float*)(ws + WS_PE);
    int*  idxT = (int*)(ws + WS_IDX);

    // B-fragment pack: out = ((ntile*8 + ktile)*64 + lane)*8 + elem
    {
        const int elem = tid & 7;
        const int lane = (tid >> 3) & 63;
        const int kt   = (tid >> 9) & 7;
        const int nt   = tid >> 12;
        const int k = kt * 32 + (lane >> 4) * 8 + elem;
        const int n = nt * 16 + (lane & 15);
        WkP[tid] = (HALF)Wk[k * EDIM + n];
        WvP[tid] = (HALF)Wv[k * EDIM + n];
        WqP[tid] = (HALF)Wq[k * EDIM + n];
        WoP[tid] = (HALF)Wout[k * EDIM + n];
    }
    // positional encoding table
    if (tid < HIS * EDIM) {
        const int t = tid >> 8;
        const int e = tid & 255;
        const float dt = expf(-(float)(e & ~1) * (9.210340371976184f / 256.0f));
        const float arg = (float)t * dt;
        PE[tid] = (e & 1) ? cosf(arg) : sinf(arg);
    }
    // adjacency one-hot -> index
    if (tid < NA * HIS) {
        const float* row = adjs + tid * NA;   // tid = n*HIS + t
        int best = 0;
        #pragma unroll
        for (int a = 0; a < NA; ++a) best = (row[a] > 0.5f) ? a : best;
        idxT[tid] = best;
    }
}

// ---------------- qh GEMM: qh = relu(q @ Wq + bq), f16 out. Tiles M=64 x N=128 ----------------
__global__ __launch_bounds__(256) void qh_gemm(
    const float* __restrict__ q,
    const float* __restrict__ bq,
    const char*  __restrict__ ws,
    char* __restrict__ wsout)
{
    const int tid = threadIdx.x, lane = tid & 63, w = tid >> 6;
    const int l15 = lane & 15, l4 = lane >> 4;
    const int bx  = blockIdx.x;              // 0..63
    const int r0  = (bx >> 1) * 64;
    const int nh  = bx & 1;
    const HALF* WqP = (const HALF*)(ws + WS_WQP);
    HALF* qh = (HALF*)(wsout + WS_QH);

    f32x4 acc[4][2];
    #pragma unroll
    for (int mt = 0; mt < 4; ++mt)
        #pragma unroll
        for (int nt = 0; nt < 2; ++nt) acc[mt][nt] = (f32x4)0.0f;

    #pragma unroll 2
    for (int kk = 0; kk < 8; ++kk) {
        half8 afr[4];
        #pragma unroll
        for (int mt = 0; mt < 4; ++mt) {
            const float* ap = &q[(size_t)(r0 + mt * 16 + l15) * EDIM + kk * 32 + l4 * 8];
            const float4 a0 = *reinterpret_cast<const float4*>(ap);
            const float4 a1 = *reinterpret_cast<const float4*>(ap + 4);
            half8 h;
            h[0] = (HALF)a0.x; h[1] = (HALF)a0.y; h[2] = (HALF)a0.z; h[3] = (HALF)a0.w;
            h[4] = (HALF)a1.x; h[5] = (HALF)a1.y; h[6] = (HALF)a1.z; h[7] = (HALF)a1.w;
            afr[mt] = h;
        }
        #pragma unroll
        for (int nt = 0; nt < 2; ++nt) {
            const int ntile = nh * 8 + w * 2 + nt;
            const half8 bfr = *reinterpret_cast<const half8*>(
                WqP + ((size_t)(ntile * 8 + kk) * 64 + lane) * 8);
            #pragma unroll
            for (int mt = 0; mt < 4; ++mt)
                acc[mt][nt] = __builtin_amdgcn_mfma_f32_16x16x32_f16(afr[mt], bfr, acc[mt][nt], 0, 0, 0);
        }
    }

    #pragma unroll
    for (int nt = 0; nt < 2; ++nt) {
        const int col = (nh * 8 + w * 2 + nt) * 16 + l15;
        const float bqa = bq[col];
        #pragma unroll
        for (int mt = 0; mt < 4; ++mt)
            #pragma unroll
            for (int r = 0; r < 4; ++r) {
                const int row = l4 * 4 + r;
                qh[(size_t)(r0 + mt * 16 + row) * EDIM + col] =
                    (HALF)fmaxf(acc[mt][nt][r] + bqa, 0.0f);
            }
    }
}

// ---------------- fused enc+attention: 1 (b,n) per block, 8 waves (1 head/wave) ----------------
// s_A granule layout: granule(row=kk*4+mt, fl) stored at (row*64 + (fl^kk)) * 8 halves.
// Fragment element (t,e): kk=e>>5, fl=((e>>3)&3)*16 + (t&15), half j=e&7.
__global__ __launch_bounds__(512, 4) void attn_fused(
    const float* __restrict__ kin,
    const float* __restrict__ bk,
    const float* __restrict__ bv,
    const float* __restrict__ Wenc,
    const char*  __restrict__ ws,
    char* __restrict__ wsout)
{
    const int tid  = threadIdx.x;
    const int lane = tid & 63;
    const int w    = tid >> 6;          // wave 0..7 -> head w (cols w*32..w*32+31)
    const int l15  = lane & 15;
    const int l4   = lane >> 4;
    const int bidx = blockIdx.x;
    const int b = bidx >> 6, n = bidx & 63;

    const HALF* WkP  = (const HALF*)(ws + WS_WKP);
    const HALF* WvP  = (const HALF*)(ws + WS_WVP);
    const HALF* qh   = (const HALF*)(ws + WS_QH);
    const float* PE  = (const float*)(ws + WS_PE);
    const int*  idxT = (const int*)(ws + WS_IDX);
    HALF* O = (HALF*)(wsout + WS_QH);   // overwrite own qh row at the end (safe per-row)

    __shared__ __align__(16) HALF  s_A[32 * 64 * 8];   // 32 KB swizzled A-frags
    __shared__ __align__(16) float s_neigh[HIS][12];
    __shared__ float s_att[NV][64];                    // wave-private rows
    __shared__ __align__(16) float s_o[EDIM];

    // ---- gather neighbor actions ----
    for (int i = tid; i < HIS * 12; i += 512) {
        const int t = i / 12;
        const int d = i - t * 12;
        float val = 0.0f;
        if (d < DKA) val = kin[((b * HIS + t) * NA + idxT[n * HIS + t]) * DKA + d];
        s_neigh[t][d] = val;
    }
    __syncthreads();

    // ---- enc phase: 4 cols/thread, 8 t-slots; branchless GELU; swizzled store ----
    {
        const int c4   = tid & 63;        // column group: e0 = c4*4
        const int slot = tid >> 6;        // 0..7
        const int e0   = c4 * 4;
        const int kk   = e0 >> 5;
        const int fg   = (e0 >> 3) & 3;
        const int sub  = (e0 >> 2) & 1;
        float4 we[DKA];
        #pragma unroll
        for (int d = 0; d < DKA; ++d)
            we[d] = *reinterpret_cast<const float4*>(&Wenc[d * EDIM + e0]);

        for (int t = slot; t < HIS; t += 8) {
            float4 x = s_neigh[t][0] * we[0];
            #pragma unroll
            for (int d = 1; d < DKA; ++d) x += s_neigh[t][d] * we[d];
            const float4 pe = *reinterpret_cast<const float4*>(&PE[t * EDIM + e0]);
            half4 hv;
            hv[0] = (HALF)(gelu_exact(x.x) + pe.x);
            hv[1] = (HALF)(gelu_exact(x.y) + pe.y);
            hv[2] = (HALF)(gelu_exact(x.z) + pe.z);
            hv[3] = (HALF)(gelu_exact(x.w) + pe.w);
            const int row = kk * 4 + (t >> 4);
            const int fl  = fg * 16 + (t & 15);
            *reinterpret_cast<half4*>(&s_A[(row * 64 + (fl ^ kk)) * 8 + sub * 4]) = hv;
        }
        // zero pad t = 50..63 (rows mt=3, t&15 in 2..15)
        const half8 z = (half8)(HALF)0.0f;
        for (int i = tid; i < 8 * 4 * 14; i += 512) {
            const int kz  = i / 56;
            const int rem = i - kz * 56;
            const int fgz = rem / 14;
            const int tz  = 2 + (rem - fgz * 14);
            const int flz = fgz * 16 + tz;
            *reinterpret_cast<half8*>(&s_A[((kz * 4 + 3) * 64 + (flz ^ kz)) * 8]) = z;
        }
    }
    __syncthreads();

    // ---- per-wave constants ----
    float qv[2], bkb[2], bvb[2];
    #pragma unroll
    for (int nt = 0; nt < 2; ++nt) {
        const int col = w * 32 + nt * 16 + l15;
        qv[nt]  = (float)qh[(size_t)bidx * EDIM + col];
        bkb[nt] = bk[col];
        bvb[nt] = bv[col];
    }

    f32x4 ka[4][2], va[4][2];
    #pragma unroll
    for (int mt = 0; mt < 4; ++mt)
        #pragma unroll
        for (int nt = 0; nt < 2; ++nt) { ka[mt][nt] = (f32x4)0.0f; va[mt][nt] = (f32x4)0.0f; }

    // ---- K-loop: dual GEMM (kh & vh), head w ----
    #pragma unroll
    for (int kk = 0; kk < 8; ++kk) {
        half8 afr[4];
        #pragma unroll
        for (int mt = 0; mt < 4; ++mt)
            afr[mt] = *reinterpret_cast<const half8*>(
                &s_A[((kk * 4 + mt) * 64 + (lane ^ kk)) * 8]);
        #pragma unroll
        for (int nt = 0; nt < 2; ++nt) {
            const size_t boff = ((size_t)((w * 2 + nt) * 8 + kk) * 64 + lane) * 8;
            const half8 bkfr = *reinterpret_cast<const half8*>(WkP + boff);
            const half8 bvfr = *reinterpret_cast<const half8*>(WvP + boff);
            #pragma unroll
            for (int mt = 0; mt < 4; ++mt) {
                ka[mt][nt] = __builtin_amdgcn_mfma_f32_16x16x32_f16(afr[mt], bkfr, ka[mt][nt], 0, 0, 0);
                va[mt][nt] = __builtin_amdgcn_mfma_f32_16x16x32_f16(afr[mt], bvfr, va[mt][nt], 0, 0, 0);
            }
        }
    }

    // ---- logits: relu(kh+bk) . qh over 32 head dims (16-lane reduce) ----
    #pragma unroll
    for (int mt = 0; mt < 4; ++mt)
        #pragma unroll
        for (int r = 0; r < 4; ++r) {
            float p = qv[0] * fmaxf(ka[mt][0][r] + bkb[0], 0.0f)
                    + qv[1] * fmaxf(ka[mt][1][r] + bkb[1], 0.0f);
            p += __shfl_xor(p, 1);
            p += __shfl_xor(p, 2);
            p += __shfl_xor(p, 4);
            p += __shfl_xor(p, 8);
            if (l15 == 0) s_att[w][mt * 16 + l4 * 4 + r] = p * (1.0f / 3.0f);
        }

    // ---- wave-wide softmax over 50 t's (lane = t) ----
    {
        const float val = (lane < HIS) ? s_att[w][lane] : -1e30f;
        float m = val;
        m = fmaxf(m, __shfl_xor(m, 1));
        m = fmaxf(m, __shfl_xor(m, 2));
        m = fmaxf(m, __shfl_xor(m, 4));
        m = fmaxf(m, __shfl_xor(m, 8));
        m = fmaxf(m, __shfl_xor(m, 16));
        m = fmaxf(m, __shfl_xor(m, 32));
        const float e = (lane < HIS) ? __expf(val - m) : 0.0f;
        float s = e;
        s += __shfl_xor(s, 1);
        s += __shfl_xor(s, 2);
        s += __shfl_xor(s, 4);
        s += __shfl_xor(s, 8);
        s += __shfl_xor(s, 16);
        s += __shfl_xor(s, 32);
        s_att[w][lane] = e * __builtin_amdgcn_rcpf(s) * (s * __builtin_amdgcn_rcpf(s));  // ~e/s
        s_att[w][lane] = e / s;
    }

    // ---- PV ----
    {
        float o0 = 0.f, o1 = 0.f;
        #pragma unroll
        for (int mt = 0; mt < 4; ++mt)
            #pragma unroll
            for (int r = 0; r < 4; ++r) {
                const int t = mt * 16 + l4 * 4 + r;
                const float a = s_att[w][t];
                o0 += a * fmaxf(va[mt][0][r] + bvb[0], 0.0f);
                o1 += a * fmaxf(va[mt][1][r] + bvb[1], 0.0f);
            }
        o0 += __shfl_xor(o0, 16); o1 += __shfl_xor(o1, 16);
        o0 += __shfl_xor(o0, 32); o1 += __shfl_xor(o1, 32);
        if (lane < 16) {
            s_o[w * 32 +  0 + l15] = o0;
            s_o[w * 32 + 16 + l15] = o1;
        }
    }
    __syncthreads();

    // ---- write O row (f16) for out_gemm ----
    if (tid < 256) O[(size_t)bidx * EDIM + tid] = (HALF)s_o[tid];
}

// ---------------- out GEMM: out = relu(O @ Wout + bout), tiles M=64 x N=128 ----------------
__global__ __launch_bounds__(256) void out_gemm(
    const float* __restrict__ bout,
    const char*  __restrict__ ws,
    float* __restrict__ out)
{
    const int tid = threadIdx.x, lane = tid & 63, w = tid >> 6;
    const int l15 = lane & 15, l4 = lane >> 4;
    const int bx  = blockIdx.x;          // 0..63
    const int r0  = (bx >> 1) * 64;
    const int nh  = bx & 1;
    const HALF* WoP = (const HALF*)(ws + WS_WOP);
    const HALF* O   = (const HALF*)(ws + WS_QH);

    f32x4 acc[4][2];
    #pragma unroll
    for (int mt = 0; mt < 4; ++mt)
        #pragma unroll
        for (int nt = 0; nt < 2; ++nt) acc[mt][nt] = (f32x4)0.0f;

    #pragma unroll 2
    for (int kk = 0; kk < 8; ++kk) {
        half8 afr[4];
        #pragma unroll
        for (int mt = 0; mt < 4; ++mt)
            afr[mt] = *reinterpret_cast<const half8*>(
                &O[(size_t)(r0 + mt * 16 + l15) * EDIM + kk * 32 + l4 * 8]);
        #pragma unroll
        for (int nt = 0; nt < 2; ++nt) {
            const int ntile = nh * 8 + w * 2 + nt;
            const half8 bfr = *reinterpret_cast<const half8*>(
                WoP + ((size_t)(ntile * 8 + kk) * 64 + lane) * 8);
            #pragma unroll
            for (int mt = 0; mt < 4; ++mt)
                acc[mt][nt] = __builtin_amdgcn_mfma_f32_16x16x32_f16(afr[mt], bfr, acc[mt][nt], 0, 0, 0);
        }
    }

    #pragma unroll
    for (int nt = 0; nt < 2; ++nt) {
        const int col = (nh * 8 + w * 2 + nt) * 16 + l15;
        const float boa = bout[col];
        #pragma unroll
        for (int mt = 0; mt < 4; ++mt)
            #pragma unroll
            for (int r = 0; r < 4; ++r) {
                const int row = l4 * 4 + r;
                out[(size_t)(r0 + mt * 16 + row) * EDIM + col] =
                    fmaxf(acc[mt][nt][r] + boa, 0.0f);
            }
    }
}

// ---------------- fallback (ws too small; f32 path) ----------------
__global__ __launch_bounds__(256) void mha_fallback(
    const float* __restrict__ q,
    const float* __restrict__ kin,
    const float* __restrict__ adjs,
    const float* __restrict__ Wq, const float* __restrict__ bq,
    const float* __restrict__ Wk, const float* __restrict__ bk,
    const float* __restrict__ Wv, const float* __restrict__ bv,
    const float* __restrict__ Wout, const float* __restrict__ bout,
    const float* __restrict__ Wenc,
    float* __restrict__ out)
{
    const int tid  = threadIdx.x;
    const int bidx = blockIdx.x;
    const int b = bidx >> 6;
    const int n = bidx & 63;

    __shared__ __align__(16) float s_q[EDIM];
    __shared__ __align__(16) float s_qh[EDIM];
    __shared__ __align__(16) float s_neigh[HIS][12];
    __shared__ __align__(16) float s_enc[HIS * EDIM];
    __shared__ float s_att[NV][66];
    __shared__ __align__(16) float s_opart[4][EDIM];
    __shared__ __align__(16) float s_o[EDIM];
    __shared__ int s_idx[HIS];

    s_q[tid] = q[bidx * EDIM + tid];
    if (tid < HIS) {
        const float* row = adjs + (n * HIS + tid) * NA;
        int best = 0;
        #pragma unroll
        for (int a = 0; a < NA; ++a) best = (row[a] > 0.5f) ? a : best;
        s_idx[tid] = best;
    }
    __syncthreads();

    for (int i = tid; i < HIS * 12; i += 256) {
        const int t = i / 12;
        const int d = i - t * 12;
        float val = 0.0f;
        if (d < DKA) val = kin[((b * HIS + t) * NA + s_idx[t]) * DKA + d];
        s_neigh[t][d] = val;
    }
    __syncthreads();

    {
        const int e = tid;
        float acc = bq[e];
        #pragma unroll 4
        for (int d0 = 0; d0 < EDIM; d0 += 4) {
            const float4 qv = *reinterpret_cast<const float4*>(&s_q[d0]);
            acc += qv.x * Wq[(d0 + 0) * EDIM + e];
            acc += qv.y * Wq[(d0 + 1) * EDIM + e];
            acc += qv.z * Wq[(d0 + 2) * EDIM + e];
            acc += qv.w * Wq[(d0 + 3) * EDIM + e];
        }
        s_qh[e] = fmaxf(acc, 0.0f);

        float we[12];
        #pragma unroll
        for (int j = 0; j < 12; ++j) we[j] = (j < DKA) ? Wenc[j * EDIM + e] : 0.0f;
        const float dt = expf(-(float)(e & ~1) * (9.210340371976184f / 256.0f));
        for (int t = 0; t < HIS; ++t) {
            const float4 n0 = *reinterpret_cast<const float4*>(&s_neigh[t][0]);
            const float4 n1 = *reinterpret_cast<const float4*>(&s_neigh[t][4]);
            const float4 n2 = *reinterpret_cast<const float4*>(&s_neigh[t][8]);
            float x = n0.x*we[0] + n0.y*we[1] + n0.z*we[2] + n0.w*we[3]
                    + n1.x*we[4] + n1.y*we[5] + n1.z*we[6] + n1.w*we[7]
                    + n2.x*we[8];
            x = 0.5f * x * (1.0f + erff(x * 0.70710678118654752f));
            const float arg = (float)t * dt;
            const float pe = (e & 1) ? cosf(arg) : sinf(arg);
            s_enc[t * EDIM + e] = x + pe;
        }
    }
    __syncthreads();

    const int g = tid & 63;
    const int h = tid >> 6;
    const int tbase  = (h == 0) ? 0 : (h == 1) ? 13 : (h == 2) ? 25 : 37;
    const int tcount = (h == 1 || h == 2) ? 12 : 13;
    const int v = g >> 3;

    {
        float4 kacc[13];
        const float4 bkv = *reinterpret_cast<const float4*>(&bk[4 * g]);
        #pragma unroll
        for (int tt = 0; tt < 13; ++tt) kacc[tt] = bkv;
        #pragma unroll 2
        for (int d0 = 0; d0 < EDIM; d0 += 4) {
            const float4 w0 = *reinterpret_cast<const float4*>(&Wk[(d0 + 0) * EDIM + 4 * g]);
            const float4 w1 = *reinterpret_cast<const float4*>(&Wk[(d0 + 1) * EDIM + 4 * g]);
            const float4 w2 = *reinterpret_cast<const float4*>(&Wk[(d0 + 2) * EDIM + 4 * g]);
            const float4 w3 = *reinterpret_cast<const float4*>(&Wk[(d0 + 3) * EDIM + 4 * g]);
            #pragma unroll
            for (int tt = 0; tt < 13; ++tt) {
                const float4 ev = *reinterpret_cast<const float4*>(&s_enc[(tbase + tt) * EDIM + d0]);
                kacc[tt].x += ev.x * w0.x + ev.y * w1.x + ev.z * w2.x + ev.w * w3.x;
                kacc[tt].y += ev.x * w0.y + ev.y * w1.y + ev.z * w2.y + ev.w * w3.y;
                kacc[tt].z += ev.x * w0.z + ev.y * w1.z + ev.z * w2.z + ev.w * w3.z;
                kacc[tt].w += ev.x * w0.w + ev.y * w1.w + ev.z * w2.w + ev.w * w3.w;
            }
        }
        const float4 qv = *reinterpret_cast<const float4*>(&s_qh[4 * g]);
        #pragma unroll
        for (int tt = 0; tt < 13; ++tt) {
            float p = qv.x * fmaxf(kacc[tt].x, 0.0f)
                    + qv.y * fmaxf(kacc[tt].y, 0.0f)
                    + qv.z * fmaxf(kacc[tt].z, 0.0f)
                    + qv.w * fmaxf(kacc[tt].w, 0.0f);
            p += __shfl_xor(p, 1);
            p += __shfl_xor(p, 2);
            p += __shfl_xor(p, 4);
            if ((g & 7) == 0) s_att[v][tbase + tt] = p * (1.0f / 3.0f);
        }
    }
    __syncthreads();

    if (tid < NV) {
        float m = -1e30f;
        for (int t = 0; t < HIS; ++t) m = fmaxf(m, s_att[tid][t]);
        float ssum = 0.0f;
        for (int t = 0; t < HIS; ++t) {
            const float ex = expf(s_att[tid][t] - m);
            s_att[tid][t] = ex;
            ssum += ex;
        }
        const float inv = 1.0f / ssum;
        for (int t = 0; t < HIS; ++t) s_att[tid][t] *= inv;
    }
    __syncthreads();

    {
        float4 vacc[13];
        const float4 bvv = *reinterpret_cast<const float4*>(&bv[4 * g]);
        #pragma unroll
        for (int tt = 0; tt < 13; ++tt) vacc[tt] = bvv;
        #pragma unroll 2
        for (int d0 = 0; d0 < EDIM; d0 += 4) {
            const float4 w0 = *reinterpret_cast<const float4*>(&Wv[(d0 + 0) * EDIM + 4 * g]);
            const float4 w1 = *reinterpret_cast<const float4*>(&Wv[(d0 + 1) * EDIM + 4 * g]);
            const float4 w2 = *reinterpret_cast<const float4*>(&Wv[(d0 + 2) * EDIM + 4 * g]);
            const float4 w3 = *reinterpret_cast<const float4*>(&Wv[(d0 + 3) * EDIM + 4 * g]);
            #pragma unroll
            for (int tt = 0; tt < 13; ++tt) {
                const float4 ev = *reinterpret_cast<const float4*>(&s_enc[(tbase + tt) * EDIM + d0]);
                vacc[tt].x += ev.x * w0.x + ev.y * w1.x + ev.z * w2.x + ev.w * w3.x;
                vacc[tt].y += ev.x * w0.y + ev.y * w1.y + ev.z * w2.y + ev.w * w3.y;
                vacc[tt].z += ev.x * w0.z + ev.y * w1.z + ev.z * w2.z + ev.w * w3.z;
                vacc[tt].w += ev.x * w0.w + ev.y * w1.w + ev.z * w2.w + ev.w * w3.w;
            }
        }
        float4 po = make_float4(0.0f, 0.0f, 0.0f, 0.0f);
        #pragma unroll
        for (int tt = 0; tt < 13; ++tt) {
            if (tt < tcount) {
                const float a = s_att[v][tbase + tt];
                po.x += a * fmaxf(vacc[tt].x, 0.0f);
                po.y += a * fmaxf(vacc[tt].y, 0.0f);
                po.z += a * fmaxf(vacc[tt].z, 0.0f);
                po.w += a * fmaxf(vacc[tt].w, 0.0f);
            }
        }
        *reinterpret_cast<float4*>(&s_opart[h][4 * g]) = po;
    }
    __syncthreads();

    s_o[tid] = s_opart[0][tid] + s_opart[1][tid] + s_opart[2][tid] + s_opart[3][tid];
    __syncthreads();

    {
        const int e = tid;
        float acc = bout[e];
        #pragma unroll 4
        for (int d0 = 0; d0 < EDIM; d0 += 4) {
            const float4 ov = *reinterpret_cast<const float4*>(&s_o[d0]);
            acc += ov.x * Wout[(d0 + 0) * EDIM + e];
            acc += ov.y * Wout[(d0 + 1) * EDIM + e];
            acc += ov.z * Wout[(d0 + 2) * EDIM + e];
            acc += ov.w * Wout[(d0 + 3) * EDIM + e];
        }
        out[bidx * EDIM + e] = fmaxf(acc, 0.0f);
    }
}

extern "C" void kernel_launch(void* const* d_in, const int* in_sizes, int n_in,
                              void* d_out, int out_size, void* d_ws, size_t ws_size,
                              hipStream_t stream) {
    const float* q    = (const float*)d_in[0];
    const float* kin  = (const float*)d_in[1];
    const float* adjs = (const float*)d_in[2];
    const float* Wq   = (const float*)d_in[3];
    const float* bq   = (const float*)d_in[4];
    const float* Wk   = (const float*)d_in[5];
    const float* bk   = (const float*)d_in[6];
    const float* Wv   = (const float*)d_in[7];
    const float* bv   = (const float*)d_in[8];
    const float* Wout = (const float*)d_in[9];
    const float* bout = (const float*)d_in[10];
    const float* Wenc = (const float*)d_in[11];
    float* out = (float*)d_out;
    char* ws = (char*)d_ws;

    if (ws_size >= WS_NEED) {
        hipLaunchKernelGGL(pack_setup, dim3(256), dim3(256), 0, stream,
                           Wk, Wv, Wq, Wout, adjs, ws);
        hipLaunchKernelGGL(qh_gemm, dim3(64), dim3(256), 0, stream,
                           q, bq, ws, ws);
        hipLaunchKernelGGL(attn_fused, dim3(NB * NA), dim3(512), 0, stream,
                           kin, bk, bv, Wenc, ws, ws);
        hipLaunchKernelGGL(out_gemm, dim3(64), dim3(256), 0, stream,
                           bout, ws, out);
    } else {
        hipLaunchKernelGGL(mha_fallback, dim3(NB * NA), dim3(256), 0, stream,
                           q, kin, adjs, Wq, bq, Wk, bk, Wv, bv, Wout, bout, Wenc, out);
    }
}

// Round 10
// 82.598 us; speedup vs baseline: 1.5545x; 1.0080x over previous
//
#include <hip/hip_runtime.h>
#include <math.h>

#define NB   32
#define NA   64
#define EDIM 256
#define HIS  50
#define DKA  9
#define NV   8

typedef _Float16 HALF;
typedef _Float16 half4 __attribute__((ext_vector_type(4)));
typedef _Float16 half8 __attribute__((ext_vector_type(8)));
typedef float    f32x4 __attribute__((ext_vector_type(4)));

// ws layout (bytes):
#define WS_WKP   0          // f16 B-frag-packed Wk                  131072
#define WS_WVP   131072     // f16 B-frag-packed Wv                  131072
#define WS_WQP   262144     // f16 B-frag-packed Wq                  131072
#define WS_WOP   393216     // f16 B-frag-packed Wout                131072
#define WS_PEH   524288     // f16 PE [50][256]                      25600
#define WS_WET   549888     // f16 WencT A-frags [me=16][lane][8]    16384
#define WS_IDX   566272     // int idxTab [64][50]                   12800
#define WS_QH    579072     // f16 [2048][256]: qh, then overwritten by O (per-row, safe)
#define WS_NEED  1627648ULL

// Branchless exact-GELU: erf via Abramowitz-Stegun 7.1.26 (|err| <= 1.5e-7)
__device__ __forceinline__ float gelu_exact(float x) {
    const float ax = fabsf(x) * 0.70710678118654752f;
    const float t  = __builtin_amdgcn_rcpf(1.0f + 0.3275911f * ax);
    const float p  = t * (0.254829592f + t * (-0.284496736f + t * (1.421413741f
                   + t * (-1.453152027f + t * 1.061405429f))));
    const float er = 1.0f - p * __expf(-ax * ax);
    return 0.5f * x * (1.0f + copysignf(er, x));
}

// ---------------- setup: pack weights (B-frag order), WencT A-frags, PE f16, adjacency ----------------
__global__ __launch_bounds__(256) void pack_setup(
    const float* __restrict__ Wk, const float* __restrict__ Wv,
    const float* __restrict__ Wq, const float* __restrict__ Wout,
    const float* __restrict__ adjs, const float* __restrict__ Wenc,
    char* __restrict__ ws)
{
    const int tid = blockIdx.x * 256 + threadIdx.x;   // 0..65535
    HALF* WkP  = (HALF*)(ws + WS_WKP);
    HALF* WvP  = (HALF*)(ws + WS_WVP);
    HALF* WqP  = (HALF*)(ws + WS_WQP);
    HALF* WoP  = (HALF*)(ws + WS_WOP);
    HALF* PEH  = (HALF*)(ws + WS_PEH);
    HALF* WET  = (HALF*)(ws + WS_WET);
    int*  idxT = (int*)(ws + WS_IDX);

    // B-fragment pack: out = ((ntile*8 + ktile)*64 + lane)*8 + elem
    {
        const int elem = tid & 7;
        const int lane = (tid >> 3) & 63;
        const int kt   = (tid >> 9) & 7;
        const int nt   = tid >> 12;
        const int k = kt * 32 + (lane >> 4) * 8 + elem;
        const int n = nt * 16 + (lane & 15);
        WkP[tid] = (HALF)Wk[k * EDIM + n];
        WvP[tid] = (HALF)Wv[k * EDIM + n];
        WqP[tid] = (HALF)Wq[k * EDIM + n];
        WoP[tid] = (HALF)Wout[k * EDIM + n];
    }
    // PE table, f16
    if (tid < HIS * EDIM) {
        const int t = tid >> 8;
        const int e = tid & 255;
        const float dt = expf(-(float)(e & ~1) * (9.210340371976184f / 256.0f));
        const float arg = (float)t * dt;
        PEH[tid] = (HALF)((e & 1) ? cosf(arg) : sinf(arg));
    }
    // WencT A-frags: WET[(me*64 + lane)*8 + j] = Wenc[k][e], k=(lane>>4)*8+j, e=me*16+(lane&15)
    if (tid < 16 * 64 * 8) {
        const int j    = tid & 7;
        const int lane = (tid >> 3) & 63;
        const int me   = tid >> 9;
        const int k = (lane >> 4) * 8 + j;
        const int e = me * 16 + (lane & 15);
        WET[tid] = (k < DKA) ? (HALF)Wenc[k * EDIM + e] : (HALF)0.0f;
    }
    // adjacency one-hot -> index
    if (tid < NA * HIS) {
        const float* row = adjs + tid * NA;   // tid = n*HIS + t
        int best = 0;
        #pragma unroll
        for (int a = 0; a < NA; ++a) best = (row[a] > 0.5f) ? a : best;
        idxT[tid] = best;
    }
}

// ---------------- qh GEMM: qh = relu(q @ Wq + bq), f16 out. Tiles M=64 x N=128 ----------------
__global__ __launch_bounds__(256) void qh_gemm(
    const float* __restrict__ q,
    const float* __restrict__ bq,
    const char*  __restrict__ ws,
    char* __restrict__ wsout)
{
    const int tid = threadIdx.x, lane = tid & 63, w = tid >> 6;
    const int l15 = lane & 15, l4 = lane >> 4;
    const int bx  = blockIdx.x;              // 0..63
    const int r0  = (bx >> 1) * 64;
    const int nh  = bx & 1;
    const HALF* WqP = (const HALF*)(ws + WS_WQP);
    HALF* qh = (HALF*)(wsout + WS_QH);

    f32x4 acc[4][2];
    #pragma unroll
    for (int mt = 0; mt < 4; ++mt)
        #pragma unroll
        for (int nt = 0; nt < 2; ++nt) acc[mt][nt] = (f32x4)0.0f;

    #pragma unroll 2
    for (int kk = 0; kk < 8; ++kk) {
        half8 afr[4];
        #pragma unroll
        for (int mt = 0; mt < 4; ++mt) {
            const float* ap = &q[(size_t)(r0 + mt * 16 + l15) * EDIM + kk * 32 + l4 * 8];
            const float4 a0 = *reinterpret_cast<const float4*>(ap);
            const float4 a1 = *reinterpret_cast<const float4*>(ap + 4);
            half8 h;
            h[0] = (HALF)a0.x; h[1] = (HALF)a0.y; h[2] = (HALF)a0.z; h[3] = (HALF)a0.w;
            h[4] = (HALF)a1.x; h[5] = (HALF)a1.y; h[6] = (HALF)a1.z; h[7] = (HALF)a1.w;
            afr[mt] = h;
        }
        #pragma unroll
        for (int nt = 0; nt < 2; ++nt) {
            const int ntile = nh * 8 + w * 2 + nt;
            const half8 bfr = *reinterpret_cast<const half8*>(
                WqP + ((size_t)(ntile * 8 + kk) * 64 + lane) * 8);
            #pragma unroll
            for (int mt = 0; mt < 4; ++mt)
                acc[mt][nt] = __builtin_amdgcn_mfma_f32_16x16x32_f16(afr[mt], bfr, acc[mt][nt], 0, 0, 0);
        }
    }

    #pragma unroll
    for (int nt = 0; nt < 2; ++nt) {
        const int col = (nh * 8 + w * 2 + nt) * 16 + l15;
        const float bqa = bq[col];
        #pragma unroll
        for (int mt = 0; mt < 4; ++mt)
            #pragma unroll
            for (int r = 0; r < 4; ++r) {
                const int row = l4 * 4 + r;
                qh[(size_t)(r0 + mt * 16 + row) * EDIM + col] =
                    (HALF)fmaxf(acc[mt][nt][r] + bqa, 0.0f);
            }
    }
}

// ---------------- fused enc+attention: 1 (b,n)/block, 8 waves, enc via MFMA ----------------
// s_A granule layout: granule(row=kk*4+mt, fl) at (row*64 + (fl^kk))*8 halves;
// holds enc[t = mt*16 + (fl&15)][e = kk*32 + (fl>>4)*8 + j].
__global__ __launch_bounds__(512, 4) void attn_fused(
    const float* __restrict__ kin,
    const float* __restrict__ bk,
    const float* __restrict__ bv,
    const char*  __restrict__ ws,
    char* __restrict__ wsout)
{
    const int tid  = threadIdx.x;
    const int lane = tid & 63;
    const int w    = tid >> 6;          // wave 0..7 -> head w (cols w*32..w*32+31)
    const int l15  = lane & 15;
    const int l4   = lane >> 4;
    const int bidx = blockIdx.x;
    const int b = bidx >> 6, n = bidx & 63;

    const HALF* WkP  = (const HALF*)(ws + WS_WKP);
    const HALF* WvP  = (const HALF*)(ws + WS_WVP);
    const HALF* PEH  = (const HALF*)(ws + WS_PEH);
    const HALF* WET  = (const HALF*)(ws + WS_WET);
    const HALF* qh   = (const HALF*)(ws + WS_QH);
    const int*  idxT = (const int*)(ws + WS_IDX);
    HALF* O = (HALF*)(wsout + WS_QH);   // overwrite own qh row at the end (safe per-row)

    __shared__ __align__(16) HALF  s_A[16384];     // 32 KB swizzled enc frags
    __shared__ __align__(16) float s_un[1280];     // 5 KB union: neighT f16 [64][40] -> s_o f32[256]
    __shared__ float s_att[NV][64];                // wave-private rows

    HALF*  s_ng = (HALF*)s_un;
    float* s_o  = s_un;

    // ---- prefetch per-wave constants early (hide under gather/enc) ----
    float qv[2], bkb[2], bvb[2];
    #pragma unroll
    for (int nt = 0; nt < 2; ++nt) {
        const int col = w * 32 + nt * 16 + l15;
        qv[nt]  = (float)qh[(size_t)bidx * EDIM + col];
        bkb[nt] = bk[col];
        bvb[nt] = bv[col];
    }

    // ---- gather neighbor actions -> f16 neighT [64][40], zero-padded k<32 ----
    #pragma unroll
    for (int i0 = 0; i0 < 64 * 32; i0 += 512) {
        const int i = i0 + tid;
        const int t = i >> 5;
        const int d = i & 31;
        float v = 0.0f;
        if (t < HIS && d < DKA)
            v = kin[((b * HIS + t) * NA + idxT[n * HIS + t]) * DKA + d];
        s_ng[t * 40 + d] = (HALF)v;
    }
    __syncthreads();

    // ---- enc phase via MFMA: encT[e][t] = gelu(WencT @ neighT) + PE -> s_A ----
    {
        half8 aW[2];
        #pragma unroll
        for (int mi = 0; mi < 2; ++mi)
            aW[mi] = *reinterpret_cast<const half8*>(WET + ((size_t)(2 * w + mi) * 64 + lane) * 8);

        f32x4 accE[2][4];
        #pragma unroll
        for (int mi = 0; mi < 2; ++mi)
            #pragma unroll
            for (int nt = 0; nt < 4; ++nt) accE[mi][nt] = (f32x4)0.0f;

        #pragma unroll
        for (int nt = 0; nt < 4; ++nt) {
            const half8 bN = *reinterpret_cast<const half8*>(&s_ng[(nt * 16 + l15) * 40 + l4 * 8]);
            #pragma unroll
            for (int mi = 0; mi < 2; ++mi)
                accE[mi][nt] = __builtin_amdgcn_mfma_f32_16x16x32_f16(aW[mi], bN, accE[mi][nt], 0, 0, 0);
        }

        // gelu + PE + half4 store into s_A fragment granules
        const int t_l = l4 & 1;     // which 8B half of the granule
        #pragma unroll
        for (int mi = 0; mi < 2; ++mi) {
            const int me = 2 * w + mi;
            const int e0 = me * 16 + l4 * 4;
            const int fg = mi * 2 + (l4 >> 1);
            #pragma unroll
            for (int nt = 0; nt < 4; ++nt) {
                const int t = nt * 16 + l15;
                half4 hv;
                if (t < HIS) {
                    const half4 pe = *reinterpret_cast<const half4*>(PEH + t * EDIM + e0);
                    hv[0] = (HALF)(gelu_exact(accE[mi][nt][0]) + (float)pe[0]);
                    hv[1] = (HALF)(gelu_exact(accE[mi][nt][1]) + (float)pe[1]);
                    hv[2] = (HALF)(gelu_exact(accE[mi][nt][2]) + (float)pe[2]);
                    hv[3] = (HALF)(gelu_exact(accE[mi][nt][3]) + (float)pe[3]);
                } else {
                    hv[0] = (HALF)0.0f; hv[1] = (HALF)0.0f;
                    hv[2] = (HALF)0.0f; hv[3] = (HALF)0.0f;
                }
                const int gran = (w * 4 + nt) * 64 + ((fg * 16 + l15) ^ w);
                *reinterpret_cast<half4*>(&s_A[gran * 8 + t_l * 4]) = hv;
            }
        }
    }
    __syncthreads();

    // ---- K-loop: dual GEMM (kh & vh), head w ----
    f32x4 ka[4][2], va[4][2];
    #pragma unroll
    for (int mt = 0; mt < 4; ++mt)
        #pragma unroll
        for (int nt = 0; nt < 2; ++nt) { ka[mt][nt] = (f32x4)0.0f; va[mt][nt] = (f32x4)0.0f; }

    #pragma unroll
    for (int kk = 0; kk < 8; ++kk) {
        half8 afr[4];
        #pragma unroll
        for (int mt = 0; mt < 4; ++mt)
            afr[mt] = *reinterpret_cast<const half8*>(
                &s_A[((kk * 4 + mt) * 64 + (lane ^ kk)) * 8]);
        #pragma unroll
        for (int nt = 0; nt < 2; ++nt) {
            const size_t boff = ((size_t)((w * 2 + nt) * 8 + kk) * 64 + lane) * 8;
            const half8 bkfr = *reinterpret_cast<const half8*>(WkP + boff);
            const half8 bvfr = *reinterpret_cast<const half8*>(WvP + boff);
            #pragma unroll
            for (int mt = 0; mt < 4; ++mt) {
                ka[mt][nt] = __builtin_amdgcn_mfma_f32_16x16x32_f16(afr[mt], bkfr, ka[mt][nt], 0, 0, 0);
                va[mt][nt] = __builtin_amdgcn_mfma_f32_16x16x32_f16(afr[mt], bvfr, va[mt][nt], 0, 0, 0);
            }
        }
    }

    // ---- logits: relu(kh+bk) . qh over 32 head dims (16-lane reduce) ----
    #pragma unroll
    for (int mt = 0; mt < 4; ++mt)
        #pragma unroll
        for (int r = 0; r < 4; ++r) {
            float p = qv[0] * fmaxf(ka[mt][0][r] + bkb[0], 0.0f)
                    + qv[1] * fmaxf(ka[mt][1][r] + bkb[1], 0.0f);
            p += __shfl_xor(p, 1);
            p += __shfl_xor(p, 2);
            p += __shfl_xor(p, 4);
            p += __shfl_xor(p, 8);
            if (l15 == 0) s_att[w][mt * 16 + l4 * 4 + r] = p * (1.0f / 3.0f);
        }

    // ---- wave-wide softmax over 50 t's (lane = t) ----
    {
        const float val = (lane < HIS) ? s_att[w][lane] : -1e30f;
        float m = val;
        m = fmaxf(m, __shfl_xor(m, 1));
        m = fmaxf(m, __shfl_xor(m, 2));
        m = fmaxf(m, __shfl_xor(m, 4));
        m = fmaxf(m, __shfl_xor(m, 8));
        m = fmaxf(m, __shfl_xor(m, 16));
        m = fmaxf(m, __shfl_xor(m, 32));
        const float e = (lane < HIS) ? __expf(val - m) : 0.0f;
        float s = e;
        s += __shfl_xor(s, 1);
        s += __shfl_xor(s, 2);
        s += __shfl_xor(s, 4);
        s += __shfl_xor(s, 8);
        s += __shfl_xor(s, 16);
        s += __shfl_xor(s, 32);
        s_att[w][lane] = e * __builtin_amdgcn_rcpf(s);
    }

    // ---- PV ----
    {
        float o0 = 0.f, o1 = 0.f;
        #pragma unroll
        for (int mt = 0; mt < 4; ++mt)
            #pragma unroll
            for (int r = 0; r < 4; ++r) {
                const int t = mt * 16 + l4 * 4 + r;
                const float a = s_att[w][t];
                o0 += a * fmaxf(va[mt][0][r] + bvb[0], 0.0f);
                o1 += a * fmaxf(va[mt][1][r] + bvb[1], 0.0f);
            }
        o0 += __shfl_xor(o0, 16); o1 += __shfl_xor(o1, 16);
        o0 += __shfl_xor(o0, 32); o1 += __shfl_xor(o1, 32);
        __syncthreads();   // s_un: all neighT reads done long ago; safe to reuse as s_o
        if (lane < 16) {
            s_o[w * 32 +  0 + l15] = o0;
            s_o[w * 32 + 16 + l15] = o1;
        }
    }
    __syncthreads();

    // ---- write O row (f16) for out_gemm ----
    if (tid < 256) O[(size_t)bidx * EDIM + tid] = (HALF)s_o[tid];
}

// ---------------- out GEMM: out = relu(O @ Wout + bout), tiles M=64 x N=128 ----------------
__global__ __launch_bounds__(256) void out_gemm(
    const float* __restrict__ bout,
    const char*  __restrict__ ws,
    float* __restrict__ out)
{
    const int tid = threadIdx.x, lane = tid & 63, w = tid >> 6;
    const int l15 = lane & 15, l4 = lane >> 4;
    const int bx  = blockIdx.x;          // 0..63
    const int r0  = (bx >> 1) * 64;
    const int nh  = bx & 1;
    const HALF* WoP = (const HALF*)(ws + WS_WOP);
    const HALF* O   = (const HALF*)(ws + WS_QH);

    f32x4 acc[4][2];
    #pragma unroll
    for (int mt = 0; mt < 4; ++mt)
        #pragma unroll
        for (int nt = 0; nt < 2; ++nt) acc[mt][nt] = (f32x4)0.0f;

    #pragma unroll 2
    for (int kk = 0; kk < 8; ++kk) {
        half8 afr[4];
        #pragma unroll
        for (int mt = 0; mt < 4; ++mt)
            afr[mt] = *reinterpret_cast<const half8*>(
                &O[(size_t)(r0 + mt * 16 + l15) * EDIM + kk * 32 + l4 * 8]);
        #pragma unroll
        for (int nt = 0; nt < 2; ++nt) {
            const int ntile = nh * 8 + w * 2 + nt;
            const half8 bfr = *reinterpret_cast<const half8*>(
                WoP + ((size_t)(ntile * 8 + kk) * 64 + lane) * 8);
            #pragma unroll
            for (int mt = 0; mt < 4; ++mt)
                acc[mt][nt] = __builtin_amdgcn_mfma_f32_16x16x32_f16(afr[mt], bfr, acc[mt][nt], 0, 0, 0);
        }
    }

    #pragma unroll
    for (int nt = 0; nt < 2; ++nt) {
        const int col = (nh * 8 + w * 2 + nt) * 16 + l15;
        const float boa = bout[col];
        #pragma unroll
        for (int mt = 0; mt < 4; ++mt)
            #pragma unroll
            for (int r = 0; r < 4; ++r) {
                const int row = l4 * 4 + r;
                out[(size_t)(r0 + mt * 16 + row) * EDIM + col] =
                    fmaxf(acc[mt][nt][r] + boa, 0.0f);
            }
    }
}

// ---------------- fallback (ws too small; f32 path) ----------------
__global__ __launch_bounds__(256) void mha_fallback(
    const float* __restrict__ q,
    const float* __restrict__ kin,
    const float* __restrict__ adjs,
    const float* __restrict__ Wq, const float* __restrict__ bq,
    const float* __restrict__ Wk, const float* __restrict__ bk,
    const float* __restrict__ Wv, const float* __restrict__ bv,
    const float* __restrict__ Wout, const float* __restrict__ bout,
    const float* __restrict__ Wenc,
    float* __restrict__ out)
{
    const int tid  = threadIdx.x;
    const int bidx = blockIdx.x;
    const int b = bidx >> 6;
    const int n = bidx & 63;

    __shared__ __align__(16) float s_q[EDIM];
    __shared__ __align__(16) float s_qh[EDIM];
    __shared__ __align__(16) float s_neigh[HIS][12];
    __shared__ __align__(16) float s_enc[HIS * EDIM];
    __shared__ float s_att[NV][66];
    __shared__ __align__(16) float s_opart[4][EDIM];
    __shared__ __align__(16) float s_o[EDIM];
    __shared__ int s_idx[HIS];

    s_q[tid] = q[bidx * EDIM + tid];
    if (tid < HIS) {
        const float* row = adjs + (n * HIS + tid) * NA;
        int best = 0;
        #pragma unroll
        for (int a = 0; a < NA; ++a) best = (row[a] > 0.5f) ? a : best;
        s_idx[tid] = best;
    }
    __syncthreads();

    for (int i = tid; i < HIS * 12; i += 256) {
        const int t = i / 12;
        const int d = i - t * 12;
        float val = 0.0f;
        if (d < DKA) val = kin[((b * HIS + t) * NA + s_idx[t]) * DKA + d];
        s_neigh[t][d] = val;
    }
    __syncthreads();

    {
        const int e = tid;
        float acc = bq[e];
        #pragma unroll 4
        for (int d0 = 0; d0 < EDIM; d0 += 4) {
            const float4 qv = *reinterpret_cast<const float4*>(&s_q[d0]);
            acc += qv.x * Wq[(d0 + 0) * EDIM + e];
            acc += qv.y * Wq[(d0 + 1) * EDIM + e];
            acc += qv.z * Wq[(d0 + 2) * EDIM + e];
            acc += qv.w * Wq[(d0 + 3) * EDIM + e];
        }
        s_qh[e] = fmaxf(acc, 0.0f);

        float we[12];
        #pragma unroll
        for (int j = 0; j < 12; ++j) we[j] = (j < DKA) ? Wenc[j * EDIM + e] : 0.0f;
        const float dt = expf(-(float)(e & ~1) * (9.210340371976184f / 256.0f));
        for (int t = 0; t < HIS; ++t) {
            const float4 n0 = *reinterpret_cast<const float4*>(&s_neigh[t][0]);
            const float4 n1 = *reinterpret_cast<const float4*>(&s_neigh[t][4]);
            const float4 n2 = *reinterpret_cast<const float4*>(&s_neigh[t][8]);
            float x = n0.x*we[0] + n0.y*we[1] + n0.z*we[2] + n0.w*we[3]
                    + n1.x*we[4] + n1.y*we[5] + n1.z*we[6] + n1.w*we[7]
                    + n2.x*we[8];
            x = 0.5f * x * (1.0f + erff(x * 0.70710678118654752f));
            const float arg = (float)t * dt;
            const float pe = (e & 1) ? cosf(arg) : sinf(arg);
            s_enc[t * EDIM + e] = x + pe;
        }
    }
    __syncthreads();

    const int g = tid & 63;
    const int h = tid >> 6;
    const int tbase  = (h == 0) ? 0 : (h == 1) ? 13 : (h == 2) ? 25 : 37;
    const int tcount = (h == 1 || h == 2) ? 12 : 13;
    const int v = g >> 3;

    {
        float4 kacc[13];
        const float4 bkv = *reinterpret_cast<const float4*>(&bk[4 * g]);
        #pragma unroll
        for (int tt = 0; tt < 13; ++tt) kacc[tt] = bkv;
        #pragma unroll 2
        for (int d0 = 0; d0 < EDIM; d0 += 4) {
            const float4 w0 = *reinterpret_cast<const float4*>(&Wk[(d0 + 0) * EDIM + 4 * g]);
            const float4 w1 = *reinterpret_cast<const float4*>(&Wk[(d0 + 1) * EDIM + 4 * g]);
            const float4 w2 = *reinterpret_cast<const float4*>(&Wk[(d0 + 2) * EDIM + 4 * g]);
            const float4 w3 = *reinterpret_cast<const float4*>(&Wk[(d0 + 3) * EDIM + 4 * g]);
            #pragma unroll
            for (int tt = 0; tt < 13; ++tt) {
                const float4 ev = *reinterpret_cast<const float4*>(&s_enc[(tbase + tt) * EDIM + d0]);
                kacc[tt].x += ev.x * w0.x + ev.y * w1.x + ev.z * w2.x + ev.w * w3.x;
                kacc[tt].y += ev.x * w0.y + ev.y * w1.y + ev.z * w2.y + ev.w * w3.y;
                kacc[tt].z += ev.x * w0.z + ev.y * w1.z + ev.z * w2.z + ev.w * w3.z;
                kacc[tt].w += ev.x * w0.w + ev.y * w1.w + ev.z * w2.w + ev.w * w3.w;
            }
        }
        const float4 qv = *reinterpret_cast<const float4*>(&s_qh[4 * g]);
        #pragma unroll
        for (int tt = 0; tt < 13; ++tt) {
            float p = qv.x * fmaxf(kacc[tt].x, 0.0f)
                    + qv.y * fmaxf(kacc[tt].y, 0.0f)
                    + qv.z * fmaxf(kacc[tt].z, 0.0f)
                    + qv.w * fmaxf(kacc[tt].w, 0.0f);
            p += __shfl_xor(p, 1);
            p += __shfl_xor(p, 2);
            p += __shfl_xor(p, 4);
            if ((g & 7) == 0) s_att[v][tbase + tt] = p * (1.0f / 3.0f);
        }
    }
    __syncthreads();

    if (tid < NV) {
        float m = -1e30f;
        for (int t = 0; t < HIS; ++t) m = fmaxf(m, s_att[tid][t]);
        float ssum = 0.0f;
        for (int t = 0; t < HIS; ++t) {
            const float ex = expf(s_att[tid][t] - m);
            s_att[tid][t] = ex;
            ssum += ex;
        }
        const float inv = 1.0f / ssum;
        for (int t = 0; t < HIS; ++t) s_att[tid][t] *= inv;
    }
    __syncthreads();

    {
        float4 vacc[13];
        const float4 bvv = *reinterpret_cast<const float4*>(&bv[4 * g]);
        #pragma unroll
        for (int tt = 0; tt < 13; ++tt) vacc[tt] = bvv;
        #pragma unroll 2
        for (int d0 = 0; d0 < EDIM; d0 += 4) {
            const float4 w0 = *reinterpret_cast<const float4*>(&Wv[(d0 + 0) * EDIM + 4 * g]);
            const float4 w1 = *reinterpret_cast<const float4*>(&Wv[(d0 + 1) * EDIM + 4 * g]);
            const float4 w2 = *reinterpret_cast<const float4*>(&Wv[(d0 + 2) * EDIM + 4 * g]);
            const float4 w3 = *reinterpret_cast<const float4*>(&Wv[(d0 + 3) * EDIM + 4 * g]);
            #pragma unroll
            for (int tt = 0; tt < 13; ++tt) {
                const float4 ev = *reinterpret_cast<const float4*>(&s_enc[(tbase + tt) * EDIM + d0]);
                vacc[tt].x += ev.x * w0.x + ev.y * w1.x + ev.z * w2.x + ev.w * w3.x;
                vacc[tt].y += ev.x * w0.y + ev.y * w1.y + ev.z * w2.y + ev.w * w3.y;
                vacc[tt].z += ev.x * w0.z + ev.y * w1.z + ev.z * w2.z + ev.w * w3.z;
                vacc[tt].w += ev.x * w0.w + ev.y * w1.w + ev.z * w2.w + ev.w * w3.w;
            }
        }
        float4 po = make_float4(0.0f, 0.0f, 0.0f, 0.0f);
        #pragma unroll
        for (int tt = 0; tt < 13; ++tt) {
            if (tt < tcount) {
                const float a = s_att[v][tbase + tt];
                po.x += a * fmaxf(vacc[tt].x, 0.0f);
                po.y += a * fmaxf(vacc[tt].y, 0.0f);
                po.z += a * fmaxf(vacc[tt].z, 0.0f);
                po.w += a * fmaxf(vacc[tt].w, 0.0f);
            }
        }
        *reinterpret_cast<float4*>(&s_opart[h][4 * g]) = po;
    }
    __syncthreads();

    s_o[tid] = s_opart[0][tid] + s_opart[1][tid] + s_opart[2][tid] + s_opart[3][tid];
    __syncthreads();

    {
        const int e = tid;
        float acc = bout[e];
        #pragma unroll 4
        for (int d0 = 0; d0 < EDIM; d0 += 4) {
            const float4 ov = *reinterpret_cast<const float4*>(&s_o[d0]);
            acc += ov.x * Wout[(d0 + 0) * EDIM + e];
            acc += ov.y * Wout[(d0 + 1) * EDIM + e];
            acc += ov.z * Wout[(d0 + 2) * EDIM + e];
            acc += ov.w * Wout[(d0 + 3) * EDIM + e];
        }
        out[bidx * EDIM + e] = fmaxf(acc, 0.0f);
    }
}

extern "C" void kernel_launch(void* const* d_in, const int* in_sizes, int n_in,
                              void* d_out, int out_size, void* d_ws, size_t ws_size,
                              hipStream_t stream) {
    const float* q    = (const float*)d_in[0];
    const float* kin  = (const float*)d_in[1];
    const float* adjs = (const float*)d_in[2];
    const float* Wq   = (const float*)d_in[3];
    const float* bq   = (const float*)d_in[4];
    const float* Wk   = (const float*)d_in[5];
    const float* bk   = (const float*)d_in[6];
    const float* Wv   = (const float*)d_in[7];
    const float* bv   = (const float*)d_in[8];
    const float* Wout = (const float*)d_in[9];
    const float* bout = (const float*)d_in[10];
    const float* Wenc = (const float*)d_in[11];
    float* out = (float*)d_out;
    char* ws = (char*)d_ws;

    if (ws_size >= WS_NEED) {
        hipLaunchKernelGGL(pack_setup, dim3(256), dim3(256), 0, stream,
                           Wk, Wv, Wq, Wout, adjs, Wenc, ws);
        hipLaunchKernelGGL(qh_gemm, dim3(64), dim3(256), 0, stream,
                           q, bq, ws, ws);
        hipLaunchKernelGGL(attn_fused, dim3(NB * NA), dim3(512), 0, stream,
                           kin, bk, bv, ws, ws);
        hipLaunchKernelGGL(out_gemm, dim3(64), dim3(256), 0, stream,
                           bout, ws, out);
    } else {
        hipLaunchKernelGGL(mha_fallback, dim3(NB * NA), dim3(256), 0, stream,
                           q, kin, adjs, Wq, bq, Wk, bk, Wv, bv, Wout, bout, Wenc, out);
    }
}